// Round 16
// baseline (1001.900 us; speedup 1.0000x reference)
//
#include <hip/hip_runtime.h>
#include <math.h>

#define NB 1024
#define NHEX 19
#define NVERT 54
#define NEDGE 72
#define NNODE 145   /* hex[0,19) vert[19,73) edge[73,145) */
#define HID 128
#define NLAYERS 3
#define MAXE 144
#define OUTD 256
#define FPLY 14
#define POOLD 398
#define ESD_PB 5120   /* floats per batch elem: 5 rels x 128 rows x 8 */

typedef unsigned short ushort_t;
typedef short bf16x8 __attribute__((ext_vector_type(8)));
typedef float f32x4 __attribute__((ext_vector_type(4)));
typedef float f32x2 __attribute__((ext_vector_type(2)));

static __device__ __forceinline__ float bf2f(ushort_t u) {
    return __uint_as_float(((unsigned int)u) << 16);
}
static __device__ __forceinline__ ushort_t f2bf(float f) {
    unsigned int u = __float_as_uint(f);
    return (ushort_t)((u + 0x7fffu + ((u >> 16) & 1u)) >> 16);
}
static __device__ __forceinline__ unsigned pk2(float lo, float hi) {
    unsigned r;
    asm("v_cvt_pk_bf16_f32 %0, %1, %2" : "=v"(r) : "v"(lo), "v"(hi));
    return r;
}
static __device__ __forceinline__ float blo(unsigned u) { return __uint_as_float(u << 16); }
static __device__ __forceinline__ float bhi(unsigned u) { return __uint_as_float(u & 0xffff0000u); }
static __device__ __forceinline__ f32x4 MF(uint4 a, uint4 b, f32x4 c) {
    return __builtin_amdgcn_mfma_f32_16x16x32_bf16(
        __builtin_bit_cast(bf16x8, a), __builtin_bit_cast(bf16x8, b), c, 0, 0, 0);
}
static __device__ __forceinline__ int xba(int row, int cb) {
    return (row * 256 + cb) ^ ((row & 7) << 4);
}

/* ================= topology (numpy RandomState(0) replica) + dedup CSR ============
   Dense dedup: edge-parallel atomic histogram M[Nd][Ns] -> parallel count/scan/rank. */
__device__ void topo_body(char* sm, int* __restrict__ cst_g, unsigned* __restrict__ pck_g) {
    unsigned* mt = (unsigned*)(sm);
    int* t6   = (int*)(sm + 2496);
    int* sc   = (int*)(sm + 4992);
    int* hv   = (int*)(sm + 7488);
    int* v0a  = (int*)(sm + 7944);
    int* v1a  = (int*)(sm + 8232);
    int* cnt  = (int*)(sm + 8520);
    int* cnt0 = (int*)(sm + 8840);
    int* stt  = (int*)(sm + 9160);
    int* J186 = (int*)(sm + 9480);
    int* M    = (int*)(sm + 9488);
    const int tid = threadIdx.x;

    if (tid == 0) {
        unsigned s = 0u;
        for (int i = 0; i < 624; ++i) { mt[i] = s; s = 1812433253u * (s ^ (s >> 30)) + (unsigned)i + 1u; }
    }
    __syncthreads();
    {
        unsigned a = 0, bb = 0, c = 0;
        if (tid < 227) { a = mt[tid]; bb = mt[tid + 1]; c = mt[tid + 397]; }
        __syncthreads();
        if (tid < 227) {
            unsigned y = (a & 0x80000000u) | (bb & 0x7fffffffu);
            mt[tid] = c ^ (y >> 1) ^ ((bb & 1u) ? 0x9908b0dfu : 0u);
        }
        __syncthreads();
    }
    {
        int i = 227 + tid;
        unsigned a = 0, bb = 0, c = 0;
        if (tid < 227) { a = mt[i]; bb = mt[i + 1]; c = mt[i - 227]; }
        __syncthreads();
        if (tid < 227) {
            unsigned y = (a & 0x80000000u) | (bb & 0x7fffffffu);
            mt[i] = c ^ (y >> 1) ^ ((bb & 1u) ? 0x9908b0dfu : 0u);
        }
        __syncthreads();
    }
    {
        int i = 454 + tid;
        unsigned a = 0, bb = 0, c = 0;
        if (tid < 170) { a = mt[i]; bb = mt[(i + 1) % 624]; c = mt[i - 227]; }
        __syncthreads();
        if (tid < 170) {
            unsigned y = (a & 0x80000000u) | (bb & 0x7fffffffu);
            mt[i] = c ^ (y >> 1) ^ ((bb & 1u) ? 0x9908b0dfu : 0u);
        }
        __syncthreads();
    }
    for (int i = tid; i < 624; i += 256) {
        unsigned y = mt[i];
        y ^= y >> 11; y ^= (y << 7) & 0x9d2c5680u; y ^= (y << 15) & 0xefc60000u; y ^= y >> 18;
        t6[i] = (int)(y & 63u);
    }
    __syncthreads();
#define SCAN624()                                                          \
    for (int off = 1; off < 624; off <<= 1) {                              \
        int v0_ = 0, v1_ = 0, v2_ = 0;                                     \
        int i0 = tid, i1 = tid + 256, i2 = tid + 512;                      \
        if (i0 >= off) v0_ = sc[i0 - off];                                 \
        if (i1 >= off) v1_ = sc[i1 - off];                                 \
        if (i2 < 624 && i2 >= off) v2_ = sc[i2 - off];                     \
        __syncthreads();                                                   \
        sc[i0] += v0_; sc[i1] += v1_;                                      \
        if (i2 < 624) sc[i2] += v2_;                                       \
        __syncthreads();                                                   \
    }
    for (int i = tid; i < 624; i += 256) sc[i] = (t6[i] <= 53) ? 1 : 0;
    __syncthreads();
    SCAN624();
    for (int i = tid; i < 624; i += 256) {
        if (t6[i] <= 53) {
            int k = sc[i];
            if (k <= 114) hv[k - 1] = t6[i];
            else if (k <= 186) v0a[k - 115] = t6[i];
            if (k == 186) *J186 = i;
        }
    }
    __syncthreads();
    int Jcap = *J186;
    for (int i = tid; i < 624; i += 256) sc[i] = (i > Jcap && t6[i] <= 52) ? 1 : 0;
    __syncthreads();
    SCAN624();
    for (int i = tid; i < 624; i += 256) {
        if (i > Jcap && t6[i] <= 52) {
            int k = sc[i];
            if (k <= 72) v1a[k - 1] = (v0a[k - 1] + 1 + t6[i]) % 54;
        }
    }
    __syncthreads();
#undef SCAN624
    const int En[5]  = {114, 114, 144, 144, 144};
    const int Ndn[5] = {54, 19, 72, 54, 54};
    const int Nsn[5] = {19, 54, 54, 72, 54};
    for (int r = 0; r < 5; ++r) {
        const int E = En[r], Nd = Ndn[r], Ns = Nsn[r];
        const int tot = Nd * Ns;
        for (int i = tid; i < tot; i += 256) M[i] = 0;
        __syncthreads();
        for (int k = tid; k < E; k += 256) {
            int s, d;
            if (r == 0)      { s = k / 6; d = hv[k]; }
            else if (r == 1) { s = hv[k]; d = k / 6; }
            else if (r == 2) { s = (k & 1) ? v1a[k >> 1] : v0a[k >> 1]; d = k >> 1; }
            else if (r == 3) { s = k >> 1; d = (k & 1) ? v1a[k >> 1] : v0a[k >> 1]; }
            else             { s = (k < 72) ? v0a[k] : v1a[k - 72]; d = (k < 72) ? v1a[k] : v0a[k - 72]; }
            atomicAdd(&M[d * Ns + s], 1);
        }
        __syncthreads();
        if (tid < Nd) {
            int c = 0;
            const int base = tid * Ns;
            for (int s = 0; s < Ns; ++s) c += (M[base + s] != 0) ? 1 : 0;
            cnt[tid] = c;
            cnt0[tid] = c;
        }
        __syncthreads();
        for (int off = 1; off < 128; off <<= 1) {
            int v = 0;
            if (tid < Nd && tid >= off) v = cnt[tid - off];
            __syncthreads();
            if (tid < Nd && tid >= off) cnt[tid] += v;
            __syncthreads();
        }
        if (tid < Nd) {
            int st = cnt[tid] - cnt0[tid];
            stt[tid] = st;
            cst_g[r * 73 + tid] = st;
            if (tid == Nd - 1) cst_g[r * 73 + Nd] = cnt[tid];
        }
        __syncthreads();
        for (int i = tid; i < tot; i += 256) {
            int m = M[i];
            if (m > 0) {
                int d = i / Ns, s = i - d * Ns;
                int rank = 0;
                const int base = d * Ns;
                for (int s2 = 0; s2 < s; ++s2) rank += (M[base + s2] != 0) ? 1 : 0;
                pck_g[r * 144 + stt[d] + rank] = (unsigned)(s | (d << 8) | (m << 16));
            }
        }
        __syncthreads();
    }
}

/* -------- attention vectors, packed 16-vec tile: h=was_hi, 4+h=wad_hi, 8+h=was_lo, 12+h=wad_lo -- */
__device__ void wvec_body(char* sm, int lr, const float* __restrict__ gat_W,
                          const float* __restrict__ gat_asrc,
                          const float* __restrict__ gat_adst,
                          ushort_t* __restrict__ wvb) {
    float* as_s = (float*)(sm);
    float* ad_s = (float*)(sm + 2048);
    int tid = threadIdx.x;
    for (int i = tid; i < 512; i += 256) {
        as_s[i] = gat_asrc[(size_t)lr * 512 + i];
        ad_s[i] = gat_adst[(size_t)lr * 512 + i];
    }
    __syncthreads();
    ushort_t* wb = wvb + (size_t)lr * 2048;
    const float* W = gat_W + (size_t)lr * 128 * 512;
    int t127 = tid & 127, rhalf = tid >> 7;
    int h = t127 >> 5, c4 = t127 & 31;
    for (int k0 = 0; k0 < 128; k0 += 2) {
        int k = k0 + rhalf;
        float4 wv4 = *(const float4*)(W + (size_t)k * 512 + h * 128 + c4 * 4);
        const float* a = as_s + h * 128 + c4 * 4;
        const float* dd = ad_s + h * 128 + c4 * 4;
        float pa = wv4.x * a[0] + wv4.y * a[1] + wv4.z * a[2] + wv4.w * a[3];
        float pd = wv4.x * dd[0] + wv4.y * dd[1] + wv4.z * dd[2] + wv4.w * dd[3];
        for (int m = 1; m < 32; m <<= 1) { pa += __shfl_xor(pa, m, 64); pd += __shfl_xor(pd, m, 64); }
        if (c4 == 0) {
            ushort_t pah = f2bf(pa), pdh = f2bf(pd);
            ushort_t pal = f2bf(pa - bf2f(pah)), pdl = f2bf(pd - bf2f(pdh));
            wb[h * 128 + k] = pah;        wb[(4 + h) * 128 + k] = pdh;
            wb[(8 + h) * 128 + k] = pal;  wb[(12 + h) * 128 + k] = pdl;
        }
    }
}

/* -------- Wp[lr][h][n][k] = bf16(gat_W[lr][k][h*128+n]) — two 64-row passes -- */
__device__ void wp_body(char* sm, int lrh, const float* __restrict__ gat_W, ushort_t* __restrict__ Wp) {
    ushort_t* tr = (ushort_t*)(sm);     /* [64][130] */
    int lr = lrh >> 2, h = lrh & 3;
    const float* Wsrc = gat_W + (size_t)lr * 128 * 512 + h * 128;
    ushort_t* dst = Wp + (size_t)lrh * 128 * 128;
    for (int half = 0; half < 2; ++half) {
        for (int i = threadIdx.x; i < 128 * 16; i += 256) {
            int k = i >> 4, q2 = i & 15;
            float4 v = *(const float4*)(Wsrc + (size_t)k * 512 + half * 64 + q2 * 4);
            int nl = q2 * 4;
            tr[(nl + 0) * 130 + k] = f2bf(v.x);
            tr[(nl + 1) * 130 + k] = f2bf(v.y);
            tr[(nl + 2) * 130 + k] = f2bf(v.z);
            tr[(nl + 3) * 130 + k] = f2bf(v.w);
        }
        __syncthreads();
        for (int i = threadIdx.x; i < 64 * 16; i += 256) {
            int nl = i >> 4, q = i & 15;
            const ushort_t* s = tr + nl * 130 + q * 8;
            uint4 o;
            o.x = (unsigned)s[0] | ((unsigned)s[1] << 16);
            o.y = (unsigned)s[2] | ((unsigned)s[3] << 16);
            o.z = (unsigned)s[4] | ((unsigned)s[5] << 16);
            o.w = (unsigned)s[6] | ((unsigned)s[7] << 16);
            *(uint4*)(dst + (half * 64 + nl) * 128 + q * 8) = o;
        }
        __syncthreads();
    }
}

/* merged prologue: block 0 topo | 1-15 wvec | 16-75 wp — shared dynamic LDS (25 KB) */
__global__ __launch_bounds__(256) void k_preA(
        int* __restrict__ cst_g, unsigned* __restrict__ pck_g,
        const float* __restrict__ gatW, const float* __restrict__ gatas,
        const float* __restrict__ gatad, ushort_t* __restrict__ wvb, ushort_t* __restrict__ Wp) {
    extern __shared__ char smem_dyn[];
    unsigned kb = blockIdx.x;
    if (kb == 0)      topo_body(smem_dyn, cst_g, pck_g);
    else if (kb < 16) wvec_body(smem_dyn, (int)kb - 1, gatW, gatas, gatad, wvb);
    else              wp_body(smem_dyn, (int)kb - 16, gatW, Wp);
}
#define PREA_SMEM 25088

/* -------- fused proj + layer-0 logits, per batch block. -------- */
__global__ __launch_bounds__(256) void k_projlog(
        const float* __restrict__ hexf, const float* __restrict__ vertf,
        const float* __restrict__ edgef,
        const float* __restrict__ Wh, const float* __restrict__ bh,
        const float* __restrict__ Wv, const float* __restrict__ bv,
        const float* __restrict__ We, const float* __restrict__ be,
        ushort_t* __restrict__ xb, const ushort_t* __restrict__ wvb,
        float* __restrict__ esd_g) {
    extern __shared__ char smem_dyn[];
    char*  smem = smem_dyn;
    float* Wl = (float*)(smem + 37120);
    float* bl = (float*)(smem + 48384);
    int b = blockIdx.x, tid = threadIdx.x, lane = tid & 63, wid = tid >> 6;
    const int kc16 = (lane >> 4) * 16;

    for (int i = tid; i < 9 * 128; i += 256) Wl[i] = Wh[i];
    for (int i = tid; i < 7 * 128; i += 256) Wl[9 * 128 + i] = Wv[i];
    for (int i = tid; i < 5 * 128; i += 256) Wl[16 * 128 + i] = We[i];
    if (tid < 128) { bl[tid] = bh[tid]; bl[128 + tid] = bv[tid]; bl[256 + tid] = be[tid]; }
    __syncthreads();
    int c = tid & 127;
    for (int n = tid >> 7; n < NNODE; n += 2) {
        const float* f; const float* W; const float* bias; int K;
        if (n < NHEX)              { f = hexf  + ((size_t)b * NHEX  + n) * 9;                  W = Wl;            bias = bl;       K = 9; }
        else if (n < NHEX + NVERT) { f = vertf + ((size_t)b * NVERT + (n - NHEX)) * 7;         W = Wl + 9 * 128;  bias = bl + 128; K = 7; }
        else                       { f = edgef + ((size_t)b * NEDGE + (n - NHEX - NVERT)) * 5; W = Wl + 16 * 128; bias = bl + 256; K = 5; }
        float acc = bias[c];
        for (int k = 0; k < K; ++k) acc += f[k] * W[k * 128 + c];
        ushort_t u = f2bf(acc);
        xb[((size_t)b * NNODE + n) * HID + c] = u;
        *(ushort_t*)(smem + xba(n, c * 2)) = u;
    }
    __syncthreads();

    const int NsA[5] = {19, 54, 54, 72, 54}, SbA[5] = {0, 19, 19, 73, 19};
    const int NdA[5] = {54, 19, 72, 54, 54}, DbA[5] = {19, 0, 73, 19, 19};
    for (int r = 0; r < 5; ++r) {
        int Ns = NsA[r];
        int RL = (r == 4) ? 54 : Ns + NdA[r];
        const ushort_t* wv = wvb + (size_t)r * 2048;
        uint4 bw[4];
#pragma unroll
        for (int ks = 0; ks < 4; ++ks)
            bw[ks] = *(const uint4*)(wv + (lane & 15) * 128 + ks * 32 + (lane >> 4) * 8);
        int T = (RL + 15) >> 4;
        for (int t = wid; t < T; t += 4) {
            int vrow = t * 16 + (lane & 15);
            int node = vrow < Ns ? SbA[r] + vrow : (vrow < RL ? DbA[r] + (vrow - Ns) : SbA[r]);
            f32x4 e = (f32x4){0.f, 0.f, 0.f, 0.f};
#pragma unroll
            for (int ks = 0; ks < 4; ++ks)
                e = MF(*(const uint4*)(smem + xba(node, ks * 64 + kc16)), bw[ks], e);
#pragma unroll
            for (int g = 0; g < 4; ++g) {
                float sv = e[g] + __shfl_xor(e[g], 8, 64);
                int row = t * 16 + (lane >> 4) * 4 + g;
                if ((lane & 15) < 8 && row < RL)
                    esd_g[(size_t)b * ESD_PB + r * 1024 + row * 8 + (lane & 15)] = sv;
            }
        }
    }
}
#define PROJLOG_SMEM 49920

/* =========== fused body. All kinds windowed; KIND1 2x36, KIND2 2x27 (R16: keeps
   doubled-y LDS at 39504 for 4 blocks/CU). 2-heads-per-pass y-build (shared extracts). ===== */
template<int KIND>
__device__ __forceinline__ void gnn_body(char* smem, int b, int half,
        const ushort_t* __restrict__ xb_cur, ushort_t* __restrict__ xb_nxt,
        const float* __restrict__ esd_cur, float* __restrict__ esd_nxt,
        const int* __restrict__ cst_all, const unsigned* __restrict__ pck_all,
        const ushort_t* __restrict__ wvb, const ushort_t* __restrict__ Wp_g,
        const float* __restrict__ gatb_g,
        const float* __restrict__ lg, const float* __restrict__ lb, int l) {
    constexpr int ND    = (KIND == 0 ? 19 : KIND == 1 ? 36 : 27);
    constexpr int DBASE = (KIND == 0 ? 0 : KIND == 1 ? 73 : 19);
    constexpr int NSMAX = (KIND == 2 ? 72 : 54);
    constexpr int NRELF = (KIND == 2 ? 3 : 1);
    constexpr int MT    = (ND + 15) / 16;
    constexpr int O_Y   = NSMAX * 256;            /* two y buffers; buf0 reused for E3 x */
    constexpr int YB1   = ND * 256;
    constexpr int O_ESD = O_Y + 2 * ND * 256;
    constexpr int O_AL  = O_ESD + 4064;
    constexpr int O_CST = O_AL + 2304;
    constexpr int O_PCK = O_CST + 304;

    constexpr int NS_A[3][3] = {{54, 0, 0}, {54, 0, 0}, {19, 72, 54}};
    constexpr int SB_A[3][3] = {{19, 0, 0}, {19, 0, 0}, {0, 73, 19}};
    constexpr int RR_A[3][3] = {{1, 0, 0}, {2, 0, 0}, {0, 3, 4}};
    constexpr int NRE = (KIND == 2 ? 5 : 2);
    constexpr int RE_R[3][5] = {{0, 1, 0, 0, 0}, {2, 3, 0, 0, 0}, {0, 1, 2, 3, 4}};
    constexpr int RE_B[3][5] = {{0, 54, 0, 0, 0}, {54, 0, 0, 0, 0}, {19, 0, 0, 72, 0}};

    float*    esdL = (float*)(smem + O_ESD);
    float*    alph = (float*)(smem + O_AL);
    int*      cstL = (int*)(smem + O_CST);
    unsigned* pckL = (unsigned*)(smem + O_PCK);

    const int tid = threadIdx.x, lane = tid & 63, wid = tid >> 6;
    const int nr0 = wid * 32 + (lane & 15);
    const int kc16 = (lane >> 4) * 16;
    const int d0 = half * ND;
    const int DB = DBASE + d0;
    const ushort_t* xcb = xb_cur + (size_t)b * NNODE * HID;

    f32x4 acc[MT][2];
#pragma unroll
    for (int mt = 0; mt < MT; ++mt) {
        acc[mt][0] = (f32x4){0.f, 0.f, 0.f, 0.f};
        acc[mt][1] = (f32x4){0.f, 0.f, 0.f, 0.f};
    }

#pragma unroll
    for (int ri = 0; ri < NRELF; ++ri) {
        const int NS = NS_A[KIND][ri], SBG = SB_A[KIND][ri], r = RR_A[KIND][ri];
        const bool SELF = (KIND == 2 && ri == 2);
        const int lr = l * 5 + r;
        const int ER = SELF ? NS : NS + ND;       /* SELF: full 54 rows carry src+dst */
        const int jlo = cst_all[r * 73 + d0];

        for (int i = tid; i < NS * 16; i += 256) {
            int row = i >> 4, q = i & 15;
            uint4 o = *(const uint4*)(xcb + (size_t)(SBG + row) * HID + q * 8);
            *(uint4*)(smem + xba(row, q * 16)) = o;
        }
        {
            const float* eg = esd_cur + (size_t)b * ESD_PB + (size_t)r * 1024;
            for (int i = tid; i < ER * 2; i += 256) {
                int row = i >> 1;
                int grow = (SELF || row < NS) ? row : row + d0;
                ((uint4*)esdL)[i] = ((const uint4*)eg)[grow * 2 + (i & 1)];
            }
        }
        for (int i = tid; i <= ND; i += 256) cstL[i] = cst_all[r * 73 + d0 + i] - jlo;
        for (int i = tid; jlo + i < 144; i += 256) pckL[i] = pck_all[r * 144 + jlo + i];
        __syncthreads();

        /* fused scores + per-(d,h) softmax -> alph */
        for (int i = tid; i < ND * 4; i += 256) {
            int d = i >> 2, h = i & 3;
            int s0 = cstL[d], s1 = cstL[d + 1];
            if (s0 == s1) continue;
            float edv = esdL[((SELF ? d + d0 : NS + d)) * 8 + 4 + h];
            float m = -1e30f;
            for (int j = s0; j < s1; ++j) {
                float sv = esdL[(pckL[j] & 255) * 8 + h] + edv;
                sv = (sv >= 0.f) ? sv : 0.2f * sv;
                alph[j * 4 + h] = sv;
                m = fmaxf(m, sv);
            }
            float sum = 0.f;
            for (int j = s0; j < s1; ++j) {
                float e = (float)(pckL[j] >> 16) * __expf(alph[j * 4 + h] - m);
                alph[j * 4 + h] = e;
                sum += e;
            }
            float inv = 1.f / (sum + 1e-16f);
            for (int j = s0; j < s1; ++j) alph[j * 4 + h] *= inv;
        }
        __syncthreads();

        /* 2 head-pairs per rel: shared-extract y-build into 2 buffers, then 2 MFMAs */
#pragma unroll
        for (int hp = 0; hp < 2; ++hp) {
            const int h0 = hp * 2;
            for (int i = tid; i < ND * 16; i += 256) {
                int d = i >> 4, c8 = i & 15;
                int s0 = cstL[d], s1 = cstL[d + 1];
                f32x2 y0a = (f32x2){0.f, 0.f}, y0b = (f32x2){0.f, 0.f};
                f32x2 y0c = (f32x2){0.f, 0.f}, y0d = (f32x2){0.f, 0.f};
                f32x2 y1a = (f32x2){0.f, 0.f}, y1b = (f32x2){0.f, 0.f};
                f32x2 y1c = (f32x2){0.f, 0.f}, y1d = (f32x2){0.f, 0.f};
                for (int j = s0; j < s1; ++j) {
                    float al0 = alph[j * 4 + h0];
                    float al1 = alph[j * 4 + h0 + 1];
                    f32x2 v0 = (f32x2){al0, al0}, v1 = (f32x2){al1, al1};
                    uint4 xv = *(const uint4*)(smem + xba((int)(pckL[j] & 255), c8 * 16));
                    f32x2 e0 = (f32x2){blo(xv.x), bhi(xv.x)};
                    f32x2 e1 = (f32x2){blo(xv.y), bhi(xv.y)};
                    f32x2 e2 = (f32x2){blo(xv.z), bhi(xv.z)};
                    f32x2 e3 = (f32x2){blo(xv.w), bhi(xv.w)};
                    y0a += v0 * e0; y0b += v0 * e1; y0c += v0 * e2; y0d += v0 * e3;
                    y1a += v1 * e0; y1b += v1 * e1; y1c += v1 * e2; y1d += v1 * e3;
                }
                uint4 o0, o1;
                o0.x = pk2(y0a[0], y0a[1]); o0.y = pk2(y0b[0], y0b[1]);
                o0.z = pk2(y0c[0], y0c[1]); o0.w = pk2(y0d[0], y0d[1]);
                o1.x = pk2(y1a[0], y1a[1]); o1.y = pk2(y1b[0], y1b[1]);
                o1.z = pk2(y1c[0], y1c[1]); o1.w = pk2(y1d[0], y1d[1]);
                int ba = xba(d, c8 * 16);
                *(uint4*)(smem + O_Y + ba) = o0;
                *(uint4*)(smem + O_Y + YB1 + ba) = o1;
            }
            const ushort_t* wpH0 = Wp_g + (size_t)(lr * 4 + h0) * 16384;
            const ushort_t* wpH1 = wpH0 + 16384;
            __syncthreads();
#pragma unroll
            for (int ks = 0; ks < 4; ++ks) {
                uint4 b00 = *(const uint4*)(wpH0 + (size_t)nr0 * 128 + ks * 32 + (lane >> 4) * 8);
                uint4 b01 = *(const uint4*)(wpH0 + (size_t)(nr0 + 16) * 128 + ks * 32 + (lane >> 4) * 8);
                uint4 b10 = *(const uint4*)(wpH1 + (size_t)nr0 * 128 + ks * 32 + (lane >> 4) * 8);
                uint4 b11 = *(const uint4*)(wpH1 + (size_t)(nr0 + 16) * 128 + ks * 32 + (lane >> 4) * 8);
#pragma unroll
                for (int mt = 0; mt < MT; ++mt) {
                    int arow = mt * 16 + (lane & 15);
                    if (arow >= ND) arow = ND - 1;
                    int ba = xba(arow, ks * 64 + kc16);
                    uint4 av0 = *(const uint4*)(smem + O_Y + ba);
                    uint4 av1 = *(const uint4*)(smem + O_Y + YB1 + ba);
                    acc[mt][0] = MF(av0, b00, acc[mt][0]);
                    acc[mt][1] = MF(av0, b01, acc[mt][1]);
                    acc[mt][0] = MF(av1, b10, acc[mt][0]);
                    acc[mt][1] = MF(av1, b11, acc[mt][1]);
                }
            }
            __syncthreads();
        }
    }

    /* epilogue: bias + residual; LN via register two-pass (in-place centering) */
    float bn0 = 0.f, bn1 = 0.f;
#pragma unroll
    for (int ri = 0; ri < NRELF; ++ri) {
        const float* bb = gatb_g + (size_t)(l * 5 + RR_A[KIND][ri]) * 128;
        bn0 += bb[nr0]; bn1 += bb[nr0 + 16];
    }
    const float lgc0 = lg[nr0], lgc1 = lg[nr0 + 16];
    const float lbc0 = lb[nr0], lbc1 = lb[nr0 + 16];
#pragma unroll
    for (int mt = 0; mt < MT; ++mt)
#pragma unroll
        for (int g = 0; g < 4; ++g) {
            int row = mt * 16 + (lane >> 4) * 4 + g;
            if (row < ND) {
                acc[mt][0][g] = 0.25f * acc[mt][0][g] + bn0 + bf2f(xcb[(size_t)(DB + row) * HID + nr0]);
                acc[mt][1][g] = 0.25f * acc[mt][1][g] + bn1 + bf2f(xcb[(size_t)(DB + row) * HID + nr0 + 16]);
            }
        }
    float* red1 = esdL;
    float* red2 = esdL + 320;
#pragma unroll
    for (int mt = 0; mt < MT; ++mt)
#pragma unroll
        for (int g = 0; g < 4; ++g) {
            float p = acc[mt][0][g] + acc[mt][1][g];
            for (int m = 1; m < 16; m <<= 1) p += __shfl_xor(p, m, 64);
            int row = mt * 16 + (lane >> 4) * 4 + g;
            if ((lane & 15) == 0 && row < ND) red1[row * 4 + wid] = p;
        }
    __syncthreads();
#pragma unroll
    for (int mt = 0; mt < MT; ++mt)
#pragma unroll
        for (int g = 0; g < 4; ++g) {
            int row = mt * 16 + (lane >> 4) * 4 + g;
            float mu = 0.f;
            if (row < ND)
                mu = (red1[row * 4] + red1[row * 4 + 1] + red1[row * 4 + 2] + red1[row * 4 + 3]) * (1.f / 128.f);
            acc[mt][0][g] -= mu;
            acc[mt][1][g] -= mu;
            float p = acc[mt][0][g] * acc[mt][0][g] + acc[mt][1][g] * acc[mt][1][g];
            for (int m = 1; m < 16; m <<= 1) p += __shfl_xor(p, m, 64);
            if ((lane & 15) == 0 && row < ND) red2[row * 4 + wid] = p;
        }
    __syncthreads();
#pragma unroll
    for (int mt = 0; mt < MT; ++mt)
#pragma unroll
        for (int g = 0; g < 4; ++g) {
            int row = mt * 16 + (lane >> 4) * 4 + g;
            if (row < ND) {
                float var = (red2[row * 4] + red2[row * 4 + 1] + red2[row * 4 + 2] + red2[row * 4 + 3]) * (1.f / 128.f);
                float rs = rsqrtf(var + 1e-5f);
                float o0 = fmaxf(acc[mt][0][g] * rs * lgc0 + lbc0, 0.f);
                float o1 = fmaxf(acc[mt][1][g] * rs * lgc1 + lbc1, 0.f);
                size_t gi = ((size_t)b * NNODE + DB + row) * HID;
                ushort_t u0 = f2bf(o0), u1 = f2bf(o1);
                xb_nxt[gi + nr0] = u0;
                xb_nxt[gi + nr0 + 16] = u1;
                if (esd_nxt) {
                    *(ushort_t*)(smem + O_Y + xba(row, nr0 * 2)) = u0;
                    *(ushort_t*)(smem + O_Y + xba(row, (nr0 + 16) * 2)) = u1;
                }
            }
        }
    if (esd_nxt) {
        __syncthreads();
        const int T = (ND + 15) >> 4;
        for (int t5 = wid; t5 < NRE * T; t5 += 4) {
            int e = t5 / T, tt = t5 % T;
            int r2 = RE_R[KIND][e], base = RE_B[KIND][e] + d0;
            const ushort_t* wv = wvb + (size_t)((l + 1) * 5 + r2) * 2048;
            uint4 bw[4];
#pragma unroll
            for (int ks = 0; ks < 4; ++ks)
                bw[ks] = *(const uint4*)(wv + (lane & 15) * 128 + ks * 32 + (lane >> 4) * 8);
            int arow = tt * 16 + (lane & 15);
            if (arow >= ND) arow = ND - 1;
            f32x4 ev = (f32x4){0.f, 0.f, 0.f, 0.f};
#pragma unroll
            for (int ks = 0; ks < 4; ++ks)
                ev = MF(*(const uint4*)(smem + O_Y + xba(arow, ks * 64 + kc16)), bw[ks], ev);
#pragma unroll
            for (int g = 0; g < 4; ++g) {
                float sv = ev[g] + __shfl_xor(ev[g], 8, 64);
                int row = tt * 16 + (lane >> 4) * 4 + g;
                if ((lane & 15) < 8 && row < ND)
                    esd_nxt[(size_t)b * ESD_PB + r2 * 1024 + (base + row) * 8 + (lane & 15)] = sv;
            }
        }
    }
}

/* LDS (all kinds): <=39504 -> 4 blocks/CU. (256,2) so allocator free up to 128 VGPR
   (R9/R11 lesson: never cap below need; <=128 still allows 4 blocks of 256 by m69 table). */
#define SMEM_TOT 39504

__global__ __launch_bounds__(256, 2) void k_layer(
        const ushort_t* __restrict__ xb_cur, ushort_t* __restrict__ xb_nxt,
        const float* __restrict__ esd_cur, float* __restrict__ esd_nxt,
        const int* __restrict__ cst, const unsigned* __restrict__ pck,
        const ushort_t* __restrict__ wvb, const ushort_t* __restrict__ Wp,
        const float* __restrict__ gatb, const float* __restrict__ lngp,
        const float* __restrict__ lnbp, int l) {
    extern __shared__ uint4 smem_u4[];
    char* smem = (char*)smem_u4;
    unsigned kb = blockIdx.x;
    if (kb < 2 * NB)
        gnn_body<2>(smem, (int)(kb >> 1), (int)(kb & 1), xb_cur, xb_nxt, esd_cur, esd_nxt, cst, pck, wvb, Wp, gatb,
                    lngp + (size_t)(l * 3 + 1) * 128, lnbp + (size_t)(l * 3 + 1) * 128, l);
    else if (kb < 4 * NB) {
        unsigned t = kb - 2 * NB;
        gnn_body<1>(smem, (int)(t >> 1), (int)(t & 1), xb_cur, xb_nxt, esd_cur, esd_nxt, cst, pck, wvb, Wp, gatb,
                    lngp + (size_t)(l * 3 + 2) * 128, lnbp + (size_t)(l * 3 + 2) * 128, l);
    } else
        gnn_body<0>(smem, (int)(kb - 4 * NB), 0, xb_cur, xb_nxt, esd_cur, esd_nxt, cst, pck, wvb, Wp, gatb,
                    lngp + (size_t)(l * 3 + 0) * 128, lnbp + (size_t)(l * 3 + 0) * 128, l);
}

/* ---------------- fused head: pools + player gather + MLP1 + MLP2 (256 threads) ---------------- */
__global__ __launch_bounds__(256) void k_head(const ushort_t* __restrict__ xb, const float* __restrict__ playerf,
                                              const int* __restrict__ curp,
                                              const float* __restrict__ W1, const float* __restrict__ b1,
                                              const float* __restrict__ W2, const float* __restrict__ b2,
                                              float* __restrict__ out) {
    __shared__ float fs[POOLD];
    __shared__ float ps[256];
    __shared__ float h1s[HID];
    int b = blockIdx.x, t = threadIdx.x;
    int c = t & 127, half = t >> 7;
    const ushort_t* xbb = xb + (size_t)b * NNODE * HID;
    float s0 = 0.f, s1 = 0.f, s2 = 0.f;
    for (int n = half; n < NHEX; n += 2)                    s0 += bf2f(xbb[n * HID + c]);
    for (int n = NHEX + half; n < NHEX + NVERT; n += 2)     s1 += bf2f(xbb[n * HID + c]);
    for (int n = NHEX + NVERT + half; n < NNODE; n += 2)    s2 += bf2f(xbb[n * HID + c]);
    ps[t] = s0; __syncthreads();
    if (half == 0) fs[c] = (ps[c] + ps[128 + c]) * (1.f / 19.f);
    __syncthreads(); ps[t] = s1; __syncthreads();
    if (half == 0) fs[128 + c] = (ps[c] + ps[128 + c]) * (1.f / 54.f);
    __syncthreads(); ps[t] = s2; __syncthreads();
    if (half == 0) fs[256 + c] = (ps[c] + ps[128 + c]) * (1.f / 72.f);
    if (t < FPLY) fs[384 + t] = playerf[((size_t)b * 4 + curp[b]) * FPLY + t];
    __syncthreads();
    float a = 0.f;
    int k0 = half * 199, k1 = half ? POOLD : 199;
    for (int k = k0; k < k1; ++k) a += fs[k] * W1[(size_t)k * HID + c];
    ps[t] = a; __syncthreads();
    if (half == 0) h1s[c] = fmaxf(b1[c] + ps[c] + ps[128 + c], 0.f);
    __syncthreads();
    float o = b2[t];
    for (int j = 0; j < HID; ++j) o += h1s[j] * W2[(size_t)j * OUTD + t];
    out[(size_t)b * OUTD + t] = o;
}

/* ---------------- workspace layout ---------------- */
static constexpr size_t alignUp(size_t v) { return (v + 255) & ~(size_t)255; }
static constexpr size_t OFF_CST  = 0;
static constexpr size_t OFF_PCK  = alignUp(OFF_CST + 5 * 73 * 4);
static constexpr size_t OFF_WVB  = alignUp(OFF_PCK + 5 * 144 * 4);
static constexpr size_t OFF_WP   = alignUp(OFF_WVB + (size_t)15 * 16 * 128 * 2);
static constexpr size_t OFF_XA   = alignUp(OFF_WP + (size_t)15 * 4 * 128 * 128 * 2);
static constexpr size_t OFF_XB2  = alignUp(OFF_XA + (size_t)NB * NNODE * HID * 2);
static constexpr size_t OFF_ESD0 = alignUp(OFF_XB2 + (size_t)NB * NNODE * HID * 2);
static constexpr size_t OFF_ESD1 = alignUp(OFF_ESD0 + (size_t)NB * ESD_PB * 4);

extern "C" void kernel_launch(void* const* d_in, const int* in_sizes, int n_in,
                              void* d_out, int out_size, void* d_ws, size_t ws_size,
                              hipStream_t stream) {
    (void)in_sizes; (void)n_in; (void)out_size; (void)ws_size;
    const float* hexf   = (const float*)d_in[0];
    const float* vertf  = (const float*)d_in[1];
    const float* edgef  = (const float*)d_in[2];
    const float* playerf= (const float*)d_in[3];
    const float* inhW   = (const float*)d_in[4];
    const float* inhb   = (const float*)d_in[5];
    const float* invW   = (const float*)d_in[6];
    const float* invb   = (const float*)d_in[7];
    const float* ineW   = (const float*)d_in[8];
    const float* ineb   = (const float*)d_in[9];
    const float* gatW   = (const float*)d_in[10];
    const float* gatas  = (const float*)d_in[11];
    const float* gatad  = (const float*)d_in[12];
    const float* gatb   = (const float*)d_in[13];
    const float* lngp   = (const float*)d_in[14];
    const float* lnbp   = (const float*)d_in[15];
    const float* mW1    = (const float*)d_in[16];
    const float* mb1    = (const float*)d_in[17];
    const float* mW2    = (const float*)d_in[18];
    const float* mb2    = (const float*)d_in[19];
    const int*   curp   = (const int*)d_in[20];
    float* out = (float*)d_out;

    char* ws = (char*)d_ws;
    int* cst        = (int*)(ws + OFF_CST);
    unsigned* pck   = (unsigned*)(ws + OFF_PCK);
    ushort_t* wvb   = (ushort_t*)(ws + OFF_WVB);
    ushort_t* Wp    = (ushort_t*)(ws + OFF_WP);
    ushort_t* xbA   = (ushort_t*)(ws + OFF_XA);
    ushort_t* xbB   = (ushort_t*)(ws + OFF_XB2);
    float* esd0     = (float*)(ws + OFF_ESD0);
    float* esd1     = (float*)(ws + OFF_ESD1);

    k_preA<<<76, 256, PREA_SMEM, stream>>>(cst, pck, gatW, gatas, gatad, wvb, Wp);
    k_projlog<<<NB, 256, PROJLOG_SMEM, stream>>>(hexf, vertf, edgef, inhW, inhb, invW, invb,
                                                 ineW, ineb, xbA, wvb, esd0);

    for (int l = 0; l < NLAYERS; ++l) {
        const ushort_t* cur = (l & 1) ? xbB : xbA;
        ushort_t* nxt = (l & 1) ? xbA : xbB;
        const float* ecur = (l & 1) ? esd1 : esd0;
        float* enxt = (l == 2) ? nullptr : ((l & 1) ? esd0 : esd1);
        k_layer<<<5 * NB, 256, SMEM_TOT, stream>>>(cur, nxt, ecur, enxt, cst, pck, wvb, Wp,
                                                   gatb, lngp, lnbp, l);
    }

    k_head<<<NB, 256, 0, stream>>>(xbB, playerf, curp, mW1, mb1, mW2, mb2, out);
}

// Round 17
// 778.986 us; speedup vs baseline: 1.2862x; 1.2862x over previous
//
#include <hip/hip_runtime.h>
#include <math.h>

#define NB 1024
#define NHEX 19
#define NVERT 54
#define NEDGE 72
#define NNODE 145   /* hex[0,19) vert[19,73) edge[73,145) */
#define HID 128
#define NLAYERS 3
#define MAXE 144
#define OUTD 256
#define FPLY 14
#define POOLD 398
#define ESD_PB 5120   /* floats per batch elem: 5 rels x 128 rows x 8 */

typedef unsigned short ushort_t;
typedef short bf16x8 __attribute__((ext_vector_type(8)));
typedef float f32x4 __attribute__((ext_vector_type(4)));
typedef float f32x2 __attribute__((ext_vector_type(2)));

static __device__ __forceinline__ float bf2f(ushort_t u) {
    return __uint_as_float(((unsigned int)u) << 16);
}
static __device__ __forceinline__ ushort_t f2bf(float f) {
    unsigned int u = __float_as_uint(f);
    return (ushort_t)((u + 0x7fffu + ((u >> 16) & 1u)) >> 16);
}
static __device__ __forceinline__ unsigned pk2(float lo, float hi) {
    unsigned r;
    asm("v_cvt_pk_bf16_f32 %0, %1, %2" : "=v"(r) : "v"(lo), "v"(hi));
    return r;
}
static __device__ __forceinline__ float blo(unsigned u) { return __uint_as_float(u << 16); }
static __device__ __forceinline__ float bhi(unsigned u) { return __uint_as_float(u & 0xffff0000u); }
static __device__ __forceinline__ f32x4 MF(uint4 a, uint4 b, f32x4 c) {
    return __builtin_amdgcn_mfma_f32_16x16x32_bf16(
        __builtin_bit_cast(bf16x8, a), __builtin_bit_cast(bf16x8, b), c, 0, 0, 0);
}
static __device__ __forceinline__ int xba(int row, int cb) {
    return (row * 256 + cb) ^ ((row & 7) << 4);
}

/* ================= topology (numpy RandomState(0) replica) + dedup CSR ============
   Dense dedup: edge-parallel atomic histogram M[Nd][Ns] -> parallel count/scan/rank. */
__device__ void topo_body(char* sm, int* __restrict__ cst_g, unsigned* __restrict__ pck_g) {
    unsigned* mt = (unsigned*)(sm);
    int* t6   = (int*)(sm + 2496);
    int* sc   = (int*)(sm + 4992);
    int* hv   = (int*)(sm + 7488);
    int* v0a  = (int*)(sm + 7944);
    int* v1a  = (int*)(sm + 8232);
    int* cnt  = (int*)(sm + 8520);
    int* cnt0 = (int*)(sm + 8840);
    int* stt  = (int*)(sm + 9160);
    int* J186 = (int*)(sm + 9480);
    int* M    = (int*)(sm + 9488);
    const int tid = threadIdx.x;

    if (tid == 0) {
        unsigned s = 0u;
        for (int i = 0; i < 624; ++i) { mt[i] = s; s = 1812433253u * (s ^ (s >> 30)) + (unsigned)i + 1u; }
    }
    __syncthreads();
    {
        unsigned a = 0, bb = 0, c = 0;
        if (tid < 227) { a = mt[tid]; bb = mt[tid + 1]; c = mt[tid + 397]; }
        __syncthreads();
        if (tid < 227) {
            unsigned y = (a & 0x80000000u) | (bb & 0x7fffffffu);
            mt[tid] = c ^ (y >> 1) ^ ((bb & 1u) ? 0x9908b0dfu : 0u);
        }
        __syncthreads();
    }
    {
        int i = 227 + tid;
        unsigned a = 0, bb = 0, c = 0;
        if (tid < 227) { a = mt[i]; bb = mt[i + 1]; c = mt[i - 227]; }
        __syncthreads();
        if (tid < 227) {
            unsigned y = (a & 0x80000000u) | (bb & 0x7fffffffu);
            mt[i] = c ^ (y >> 1) ^ ((bb & 1u) ? 0x9908b0dfu : 0u);
        }
        __syncthreads();
    }
    {
        int i = 454 + tid;
        unsigned a = 0, bb = 0, c = 0;
        if (tid < 170) { a = mt[i]; bb = mt[(i + 1) % 624]; c = mt[i - 227]; }
        __syncthreads();
        if (tid < 170) {
            unsigned y = (a & 0x80000000u) | (bb & 0x7fffffffu);
            mt[i] = c ^ (y >> 1) ^ ((bb & 1u) ? 0x9908b0dfu : 0u);
        }
        __syncthreads();
    }
    for (int i = tid; i < 624; i += 256) {
        unsigned y = mt[i];
        y ^= y >> 11; y ^= (y << 7) & 0x9d2c5680u; y ^= (y << 15) & 0xefc60000u; y ^= y >> 18;
        t6[i] = (int)(y & 63u);
    }
    __syncthreads();
#define SCAN624()                                                          \
    for (int off = 1; off < 624; off <<= 1) {                              \
        int v0_ = 0, v1_ = 0, v2_ = 0;                                     \
        int i0 = tid, i1 = tid + 256, i2 = tid + 512;                      \
        if (i0 >= off) v0_ = sc[i0 - off];                                 \
        if (i1 >= off) v1_ = sc[i1 - off];                                 \
        if (i2 < 624 && i2 >= off) v2_ = sc[i2 - off];                     \
        __syncthreads();                                                   \
        sc[i0] += v0_; sc[i1] += v1_;                                      \
        if (i2 < 624) sc[i2] += v2_;                                       \
        __syncthreads();                                                   \
    }
    for (int i = tid; i < 624; i += 256) sc[i] = (t6[i] <= 53) ? 1 : 0;
    __syncthreads();
    SCAN624();
    for (int i = tid; i < 624; i += 256) {
        if (t6[i] <= 53) {
            int k = sc[i];
            if (k <= 114) hv[k - 1] = t6[i];
            else if (k <= 186) v0a[k - 115] = t6[i];
            if (k == 186) *J186 = i;
        }
    }
    __syncthreads();
    int Jcap = *J186;
    for (int i = tid; i < 624; i += 256) sc[i] = (i > Jcap && t6[i] <= 52) ? 1 : 0;
    __syncthreads();
    SCAN624();
    for (int i = tid; i < 624; i += 256) {
        if (i > Jcap && t6[i] <= 52) {
            int k = sc[i];
            if (k <= 72) v1a[k - 1] = (v0a[k - 1] + 1 + t6[i]) % 54;
        }
    }
    __syncthreads();
#undef SCAN624
    const int En[5]  = {114, 114, 144, 144, 144};
    const int Ndn[5] = {54, 19, 72, 54, 54};
    const int Nsn[5] = {19, 54, 54, 72, 54};
    for (int r = 0; r < 5; ++r) {
        const int E = En[r], Nd = Ndn[r], Ns = Nsn[r];
        const int tot = Nd * Ns;
        for (int i = tid; i < tot; i += 256) M[i] = 0;
        __syncthreads();
        for (int k = tid; k < E; k += 256) {
            int s, d;
            if (r == 0)      { s = k / 6; d = hv[k]; }
            else if (r == 1) { s = hv[k]; d = k / 6; }
            else if (r == 2) { s = (k & 1) ? v1a[k >> 1] : v0a[k >> 1]; d = k >> 1; }
            else if (r == 3) { s = k >> 1; d = (k & 1) ? v1a[k >> 1] : v0a[k >> 1]; }
            else             { s = (k < 72) ? v0a[k] : v1a[k - 72]; d = (k < 72) ? v1a[k] : v0a[k - 72]; }
            atomicAdd(&M[d * Ns + s], 1);
        }
        __syncthreads();
        if (tid < Nd) {
            int c = 0;
            const int base = tid * Ns;
            for (int s = 0; s < Ns; ++s) c += (M[base + s] != 0) ? 1 : 0;
            cnt[tid] = c;
            cnt0[tid] = c;
        }
        __syncthreads();
        for (int off = 1; off < 128; off <<= 1) {
            int v = 0;
            if (tid < Nd && tid >= off) v = cnt[tid - off];
            __syncthreads();
            if (tid < Nd && tid >= off) cnt[tid] += v;
            __syncthreads();
        }
        if (tid < Nd) {
            int st = cnt[tid] - cnt0[tid];
            stt[tid] = st;
            cst_g[r * 73 + tid] = st;
            if (tid == Nd - 1) cst_g[r * 73 + Nd] = cnt[tid];
        }
        __syncthreads();
        for (int i = tid; i < tot; i += 256) {
            int m = M[i];
            if (m > 0) {
                int d = i / Ns, s = i - d * Ns;
                int rank = 0;
                const int base = d * Ns;
                for (int s2 = 0; s2 < s; ++s2) rank += (M[base + s2] != 0) ? 1 : 0;
                pck_g[r * 144 + stt[d] + rank] = (unsigned)(s | (d << 8) | (m << 16));
            }
        }
        __syncthreads();
    }
}

/* -------- attention vectors, packed 16-vec tile: h=was_hi, 4+h=wad_hi, 8+h=was_lo, 12+h=wad_lo -- */
__device__ void wvec_body(char* sm, int lr, const float* __restrict__ gat_W,
                          const float* __restrict__ gat_asrc,
                          const float* __restrict__ gat_adst,
                          ushort_t* __restrict__ wvb) {
    float* as_s = (float*)(sm);
    float* ad_s = (float*)(sm + 2048);
    int tid = threadIdx.x;
    for (int i = tid; i < 512; i += 256) {
        as_s[i] = gat_asrc[(size_t)lr * 512 + i];
        ad_s[i] = gat_adst[(size_t)lr * 512 + i];
    }
    __syncthreads();
    ushort_t* wb = wvb + (size_t)lr * 2048;
    const float* W = gat_W + (size_t)lr * 128 * 512;
    int t127 = tid & 127, rhalf = tid >> 7;
    int h = t127 >> 5, c4 = t127 & 31;
    for (int k0 = 0; k0 < 128; k0 += 2) {
        int k = k0 + rhalf;
        float4 wv4 = *(const float4*)(W + (size_t)k * 512 + h * 128 + c4 * 4);
        const float* a = as_s + h * 128 + c4 * 4;
        const float* dd = ad_s + h * 128 + c4 * 4;
        float pa = wv4.x * a[0] + wv4.y * a[1] + wv4.z * a[2] + wv4.w * a[3];
        float pd = wv4.x * dd[0] + wv4.y * dd[1] + wv4.z * dd[2] + wv4.w * dd[3];
        for (int m = 1; m < 32; m <<= 1) { pa += __shfl_xor(pa, m, 64); pd += __shfl_xor(pd, m, 64); }
        if (c4 == 0) {
            ushort_t pah = f2bf(pa), pdh = f2bf(pd);
            ushort_t pal = f2bf(pa - bf2f(pah)), pdl = f2bf(pd - bf2f(pdh));
            wb[h * 128 + k] = pah;        wb[(4 + h) * 128 + k] = pdh;
            wb[(8 + h) * 128 + k] = pal;  wb[(12 + h) * 128 + k] = pdl;
        }
    }
}

/* -------- Wp[lr][h][n][k] = bf16(gat_W[lr][k][h*128+n]) — two 64-row passes -- */
__device__ void wp_body(char* sm, int lrh, const float* __restrict__ gat_W, ushort_t* __restrict__ Wp) {
    ushort_t* tr = (ushort_t*)(sm);     /* [64][130] */
    int lr = lrh >> 2, h = lrh & 3;
    const float* Wsrc = gat_W + (size_t)lr * 128 * 512 + h * 128;
    ushort_t* dst = Wp + (size_t)lrh * 128 * 128;
    for (int half = 0; half < 2; ++half) {
        for (int i = threadIdx.x; i < 128 * 16; i += 256) {
            int k = i >> 4, q2 = i & 15;
            float4 v = *(const float4*)(Wsrc + (size_t)k * 512 + half * 64 + q2 * 4);
            int nl = q2 * 4;
            tr[(nl + 0) * 130 + k] = f2bf(v.x);
            tr[(nl + 1) * 130 + k] = f2bf(v.y);
            tr[(nl + 2) * 130 + k] = f2bf(v.z);
            tr[(nl + 3) * 130 + k] = f2bf(v.w);
        }
        __syncthreads();
        for (int i = threadIdx.x; i < 64 * 16; i += 256) {
            int nl = i >> 4, q = i & 15;
            const ushort_t* s = tr + nl * 130 + q * 8;
            uint4 o;
            o.x = (unsigned)s[0] | ((unsigned)s[1] << 16);
            o.y = (unsigned)s[2] | ((unsigned)s[3] << 16);
            o.z = (unsigned)s[4] | ((unsigned)s[5] << 16);
            o.w = (unsigned)s[6] | ((unsigned)s[7] << 16);
            *(uint4*)(dst + (half * 64 + nl) * 128 + q * 8) = o;
        }
        __syncthreads();
    }
}

/* merged prologue: block 0 topo | 1-15 wvec | 16-75 wp — shared dynamic LDS (25 KB) */
__global__ __launch_bounds__(256) void k_preA(
        int* __restrict__ cst_g, unsigned* __restrict__ pck_g,
        const float* __restrict__ gatW, const float* __restrict__ gatas,
        const float* __restrict__ gatad, ushort_t* __restrict__ wvb, ushort_t* __restrict__ Wp) {
    extern __shared__ char smem_dyn[];
    unsigned kb = blockIdx.x;
    if (kb == 0)      topo_body(smem_dyn, cst_g, pck_g);
    else if (kb < 16) wvec_body(smem_dyn, (int)kb - 1, gatW, gatas, gatad, wvb);
    else              wp_body(smem_dyn, (int)kb - 16, gatW, Wp);
}
#define PREA_SMEM 25088

/* -------- fused proj + layer-0 logits, per batch block. -------- */
__global__ __launch_bounds__(256) void k_projlog(
        const float* __restrict__ hexf, const float* __restrict__ vertf,
        const float* __restrict__ edgef,
        const float* __restrict__ Wh, const float* __restrict__ bh,
        const float* __restrict__ Wv, const float* __restrict__ bv,
        const float* __restrict__ We, const float* __restrict__ be,
        ushort_t* __restrict__ xb, const ushort_t* __restrict__ wvb,
        float* __restrict__ esd_g) {
    extern __shared__ char smem_dyn[];
    char*  smem = smem_dyn;
    float* Wl = (float*)(smem + 37120);
    float* bl = (float*)(smem + 48384);
    int b = blockIdx.x, tid = threadIdx.x, lane = tid & 63, wid = tid >> 6;
    const int kc16 = (lane >> 4) * 16;

    for (int i = tid; i < 9 * 128; i += 256) Wl[i] = Wh[i];
    for (int i = tid; i < 7 * 128; i += 256) Wl[9 * 128 + i] = Wv[i];
    for (int i = tid; i < 5 * 128; i += 256) Wl[16 * 128 + i] = We[i];
    if (tid < 128) { bl[tid] = bh[tid]; bl[128 + tid] = bv[tid]; bl[256 + tid] = be[tid]; }
    __syncthreads();
    int c = tid & 127;
    for (int n = tid >> 7; n < NNODE; n += 2) {
        const float* f; const float* W; const float* bias; int K;
        if (n < NHEX)              { f = hexf  + ((size_t)b * NHEX  + n) * 9;                  W = Wl;            bias = bl;       K = 9; }
        else if (n < NHEX + NVERT) { f = vertf + ((size_t)b * NVERT + (n - NHEX)) * 7;         W = Wl + 9 * 128;  bias = bl + 128; K = 7; }
        else                       { f = edgef + ((size_t)b * NEDGE + (n - NHEX - NVERT)) * 5; W = Wl + 16 * 128; bias = bl + 256; K = 5; }
        float acc = bias[c];
        for (int k = 0; k < K; ++k) acc += f[k] * W[k * 128 + c];
        ushort_t u = f2bf(acc);
        xb[((size_t)b * NNODE + n) * HID + c] = u;
        *(ushort_t*)(smem + xba(n, c * 2)) = u;
    }
    __syncthreads();

    const int NsA[5] = {19, 54, 54, 72, 54}, SbA[5] = {0, 19, 19, 73, 19};
    const int NdA[5] = {54, 19, 72, 54, 54}, DbA[5] = {19, 0, 73, 19, 19};
    for (int r = 0; r < 5; ++r) {
        int Ns = NsA[r];
        int RL = (r == 4) ? 54 : Ns + NdA[r];
        const ushort_t* wv = wvb + (size_t)r * 2048;
        uint4 bw[4];
#pragma unroll
        for (int ks = 0; ks < 4; ++ks)
            bw[ks] = *(const uint4*)(wv + (lane & 15) * 128 + ks * 32 + (lane >> 4) * 8);
        int T = (RL + 15) >> 4;
        for (int t = wid; t < T; t += 4) {
            int vrow = t * 16 + (lane & 15);
            int node = vrow < Ns ? SbA[r] + vrow : (vrow < RL ? DbA[r] + (vrow - Ns) : SbA[r]);
            f32x4 e = (f32x4){0.f, 0.f, 0.f, 0.f};
#pragma unroll
            for (int ks = 0; ks < 4; ++ks)
                e = MF(*(const uint4*)(smem + xba(node, ks * 64 + kc16)), bw[ks], e);
#pragma unroll
            for (int g = 0; g < 4; ++g) {
                float sv = e[g] + __shfl_xor(e[g], 8, 64);
                int row = t * 16 + (lane >> 4) * 4 + g;
                if ((lane & 15) < 8 && row < RL)
                    esd_g[(size_t)b * ESD_PB + r * 1024 + row * 8 + (lane & 15)] = sv;
            }
        }
    }
}
#define PROJLOG_SMEM 49920

/* =========== fused body: stage + softmax + y-build + MFMA2 + LN + next-layer logits.
   KIND1 (edge) runs as 2 half-blocks of 36 rows (MT 5->3, spill fix, R11 post-mortem). ===== */
template<int KIND>
__device__ __forceinline__ void gnn_body(char* smem, int b, int half,
        const ushort_t* __restrict__ xb_cur, ushort_t* __restrict__ xb_nxt,
        const float* __restrict__ esd_cur, float* __restrict__ esd_nxt,
        const int* __restrict__ cst_all, const unsigned* __restrict__ pck_all,
        const ushort_t* __restrict__ wvb, const ushort_t* __restrict__ Wp_g,
        const float* __restrict__ gatb_g,
        const float* __restrict__ lg, const float* __restrict__ lb, int l) {
    constexpr int ND    = (KIND == 0 ? 19 : KIND == 1 ? 36 : 54);
    constexpr int DBASE = (KIND == 0 ? 0 : KIND == 1 ? 73 : 19);
    constexpr int NSMAX = (KIND == 2 ? 72 : 54);
    constexpr int NRELF = (KIND == 2 ? 3 : 1);
    constexpr int MT    = (ND + 15) / 16;
    constexpr int O_Y   = NSMAX * 256;
    constexpr int O_ESD = O_Y + ND * 256;
    constexpr int O_AL  = O_ESD + 4064;
    constexpr int O_CST = O_AL + 2304;
    constexpr int O_PCK = O_CST + 304;

    constexpr int NS_A[3][3] = {{54, 0, 0}, {54, 0, 0}, {19, 72, 54}};
    constexpr int SB_A[3][3] = {{19, 0, 0}, {19, 0, 0}, {0, 73, 19}};
    constexpr int RR_A[3][3] = {{1, 0, 0}, {2, 0, 0}, {0, 3, 4}};
    constexpr int NRE = (KIND == 2 ? 5 : 2);
    constexpr int RE_R[3][5] = {{0, 1, 0, 0, 0}, {2, 3, 0, 0, 0}, {0, 1, 2, 3, 4}};
    constexpr int RE_B[3][5] = {{0, 54, 0, 0, 0}, {54, 0, 0, 0, 0}, {19, 0, 0, 72, 0}};

    float*    esdL = (float*)(smem + O_ESD);
    float*    alph = (float*)(smem + O_AL);
    int*      cstL = (int*)(smem + O_CST);
    unsigned* pckL = (unsigned*)(smem + O_PCK);

    const int tid = threadIdx.x, lane = tid & 63, wid = tid >> 6;
    const int nr0 = wid * 32 + (lane & 15);
    const int kc16 = (lane >> 4) * 16;
    const int d0 = half * ND;
    const int DB = DBASE + d0;
    const ushort_t* xcb = xb_cur + (size_t)b * NNODE * HID;

    f32x4 acc[MT][2];
#pragma unroll
    for (int mt = 0; mt < MT; ++mt) {
        acc[mt][0] = (f32x4){0.f, 0.f, 0.f, 0.f};
        acc[mt][1] = (f32x4){0.f, 0.f, 0.f, 0.f};
    }

#pragma unroll
    for (int ri = 0; ri < NRELF; ++ri) {
        const int NS = NS_A[KIND][ri], SBG = SB_A[KIND][ri], r = RR_A[KIND][ri];
        const bool SELF = (KIND == 2 && ri == 2);
        const int lr = l * 5 + r;
        const int ER = SELF ? ND : NS + ND;
        const int jlo = cst_all[r * 73 + d0];

        for (int i = tid; i < NS * 16; i += 256) {
            int row = i >> 4, q = i & 15;
            uint4 o = *(const uint4*)(xcb + (size_t)(SBG + row) * HID + q * 8);
            *(uint4*)(smem + xba(row, q * 16)) = o;
        }
        {
            const float* eg = esd_cur + (size_t)b * ESD_PB + (size_t)r * 1024;
            for (int i = tid; i < ER * 2; i += 256) {
                int row = i >> 1;
                int grow = (SELF || row < NS) ? row : row + d0;
                ((uint4*)esdL)[i] = ((const uint4*)eg)[grow * 2 + (i & 1)];
            }
        }
        for (int i = tid; i <= ND; i += 256) cstL[i] = cst_all[r * 73 + d0 + i] - jlo;
        for (int i = tid; jlo + i < 144; i += 256) pckL[i] = pck_all[r * 144 + jlo + i];
        __syncthreads();

        for (int i = tid; i < ND * 4; i += 256) {
            int d = i >> 2, h = i & 3;
            int s0 = cstL[d], s1 = cstL[d + 1];
            if (s0 == s1) continue;
            float edv = esdL[((SELF ? d + d0 : NS + d)) * 8 + 4 + h];
            float m = -1e30f;
            for (int j = s0; j < s1; ++j) {
                float sv = esdL[(pckL[j] & 255) * 8 + h] + edv;
                sv = (sv >= 0.f) ? sv : 0.2f * sv;
                alph[j * 4 + h] = sv;
                m = fmaxf(m, sv);
            }
            float sum = 0.f;
            for (int j = s0; j < s1; ++j) {
                float e = (float)(pckL[j] >> 16) * __expf(alph[j * 4 + h] - m);
                alph[j * 4 + h] = e;
                sum += e;
            }
            float inv = 1.f / (sum + 1e-16f);
            for (int j = s0; j < s1; ++j) alph[j * 4 + h] *= inv;
        }
        __syncthreads();

        for (int h = 0; h < 4; ++h) {
            for (int i = tid; i < ND * 16; i += 256) {
                int d = i >> 4, c8 = i & 15;
                int s0 = cstL[d], s1 = cstL[d + 1];
                f32x2 a01 = (f32x2){0.f, 0.f}, a23 = (f32x2){0.f, 0.f};
                f32x2 a45 = (f32x2){0.f, 0.f}, a67 = (f32x2){0.f, 0.f};
                for (int j = s0; j < s1; ++j) {
                    float al = alph[j * 4 + h];
                    f32x2 al2 = (f32x2){al, al};
                    uint4 xv = *(const uint4*)(smem + xba((int)(pckL[j] & 255), c8 * 16));
                    a01 += al2 * (f32x2){blo(xv.x), bhi(xv.x)};
                    a23 += al2 * (f32x2){blo(xv.y), bhi(xv.y)};
                    a45 += al2 * (f32x2){blo(xv.z), bhi(xv.z)};
                    a67 += al2 * (f32x2){blo(xv.w), bhi(xv.w)};
                }
                uint4 o;
                o.x = pk2(a01[0], a01[1]); o.y = pk2(a23[0], a23[1]);
                o.z = pk2(a45[0], a45[1]); o.w = pk2(a67[0], a67[1]);
                *(uint4*)(smem + O_Y + xba(d, c8 * 16)) = o;
            }
            const ushort_t* wpH = Wp_g + (size_t)(lr * 4 + h) * 16384;
            __syncthreads();
#pragma unroll
            for (int ks = 0; ks < 4; ++ks) {
                uint4 b0 = *(const uint4*)(wpH + (size_t)nr0 * 128 + ks * 32 + (lane >> 4) * 8);
                uint4 b1 = *(const uint4*)(wpH + (size_t)(nr0 + 16) * 128 + ks * 32 + (lane >> 4) * 8);
#pragma unroll
                for (int mt = 0; mt < MT; ++mt) {
                    int arow = mt * 16 + (lane & 15);
                    if (arow >= ND) arow = ND - 1;
                    uint4 av = *(const uint4*)(smem + O_Y + xba(arow, ks * 64 + kc16));
                    acc[mt][0] = MF(av, b0, acc[mt][0]);
                    acc[mt][1] = MF(av, b1, acc[mt][1]);
                }
            }
            __syncthreads();
        }
    }

    /* epilogue */
    float bn0 = 0.f, bn1 = 0.f;
#pragma unroll
    for (int ri = 0; ri < NRELF; ++ri) {
        const float* bb = gatb_g + (size_t)(l * 5 + RR_A[KIND][ri]) * 128;
        bn0 += bb[nr0]; bn1 += bb[nr0 + 16];
    }
    const float lgc0 = lg[nr0], lgc1 = lg[nr0 + 16];
    const float lbc0 = lb[nr0], lbc1 = lb[nr0 + 16];
#pragma unroll
    for (int mt = 0; mt < MT; ++mt)
#pragma unroll
        for (int g = 0; g < 4; ++g) {
            int row = mt * 16 + (lane >> 4) * 4 + g;
            if (row < ND) {
                acc[mt][0][g] = 0.25f * acc[mt][0][g] + bn0 + bf2f(xcb[(size_t)(DB + row) * HID + nr0]);
                acc[mt][1][g] = 0.25f * acc[mt][1][g] + bn1 + bf2f(xcb[(size_t)(DB + row) * HID + nr0 + 16]);
            }
        }
    float* red1 = esdL;
    float* red2 = esdL + 320;
#pragma unroll
    for (int mt = 0; mt < MT; ++mt)
#pragma unroll
        for (int g = 0; g < 4; ++g) {
            float p = acc[mt][0][g] + acc[mt][1][g];
            for (int m = 1; m < 16; m <<= 1) p += __shfl_xor(p, m, 64);
            int row = mt * 16 + (lane >> 4) * 4 + g;
            if ((lane & 15) == 0 && row < ND) red1[row * 4 + wid] = p;
        }
    __syncthreads();
#pragma unroll
    for (int mt = 0; mt < MT; ++mt)
#pragma unroll
        for (int g = 0; g < 4; ++g) {
            int row = mt * 16 + (lane >> 4) * 4 + g;
            float mu = 0.f;
            if (row < ND)
                mu = (red1[row * 4] + red1[row * 4 + 1] + red1[row * 4 + 2] + red1[row * 4 + 3]) * (1.f / 128.f);
            acc[mt][0][g] -= mu;
            acc[mt][1][g] -= mu;
            float p = acc[mt][0][g] * acc[mt][0][g] + acc[mt][1][g] * acc[mt][1][g];
            for (int m = 1; m < 16; m <<= 1) p += __shfl_xor(p, m, 64);
            if ((lane & 15) == 0 && row < ND) red2[row * 4 + wid] = p;
        }
    __syncthreads();
#pragma unroll
    for (int mt = 0; mt < MT; ++mt)
#pragma unroll
        for (int g = 0; g < 4; ++g) {
            int row = mt * 16 + (lane >> 4) * 4 + g;
            if (row < ND) {
                float var = (red2[row * 4] + red2[row * 4 + 1] + red2[row * 4 + 2] + red2[row * 4 + 3]) * (1.f / 128.f);
                float rs = rsqrtf(var + 1e-5f);
                float o0 = fmaxf(acc[mt][0][g] * rs * lgc0 + lbc0, 0.f);
                float o1 = fmaxf(acc[mt][1][g] * rs * lgc1 + lbc1, 0.f);
                size_t gi = ((size_t)b * NNODE + DB + row) * HID;
                ushort_t u0 = f2bf(o0), u1 = f2bf(o1);
                xb_nxt[gi + nr0] = u0;
                xb_nxt[gi + nr0 + 16] = u1;
                if (esd_nxt) {
                    *(ushort_t*)(smem + O_Y + xba(row, nr0 * 2)) = u0;
                    *(ushort_t*)(smem + O_Y + xba(row, (nr0 + 16) * 2)) = u1;
                }
            }
        }
    if (esd_nxt) {
        __syncthreads();
        const int T = (ND + 15) >> 4;
        for (int t5 = wid; t5 < NRE * T; t5 += 4) {
            int e = t5 / T, tt = t5 % T;
            int r2 = RE_R[KIND][e], base = RE_B[KIND][e] + d0;
            const ushort_t* wv = wvb + (size_t)((l + 1) * 5 + r2) * 2048;
            uint4 bw[4];
#pragma unroll
            for (int ks = 0; ks < 4; ++ks)
                bw[ks] = *(const uint4*)(wv + (lane & 15) * 128 + ks * 32 + (lane >> 4) * 8);
            int arow = tt * 16 + (lane & 15);
            if (arow >= ND) arow = ND - 1;
            f32x4 ev = (f32x4){0.f, 0.f, 0.f, 0.f};
#pragma unroll
            for (int ks = 0; ks < 4; ++ks)
                ev = MF(*(const uint4*)(smem + O_Y + xba(arow, ks * 64 + kc16)), bw[ks], ev);
#pragma unroll
            for (int g = 0; g < 4; ++g) {
                float sv = ev[g] + __shfl_xor(ev[g], 8, 64);
                int row = tt * 16 + (lane >> 4) * 4 + g;
                if ((lane & 15) < 8 && row < ND)
                    esd_nxt[(size_t)b * ESD_PB + r2 * 1024 + (base + row) * 8 + (lane & 15)] = sv;
            }
        }
    }
}

#define SMEM_TOT 39504

__global__ __launch_bounds__(256, 4) void k_layer(
        const ushort_t* __restrict__ xb_cur, ushort_t* __restrict__ xb_nxt,
        const float* __restrict__ esd_cur, float* __restrict__ esd_nxt,
        const int* __restrict__ cst, const unsigned* __restrict__ pck,
        const ushort_t* __restrict__ wvb, const ushort_t* __restrict__ Wp,
        const float* __restrict__ gatb, const float* __restrict__ lngp,
        const float* __restrict__ lnbp, int l) {
    extern __shared__ uint4 smem_u4[];
    char* smem = (char*)smem_u4;
    unsigned kb = blockIdx.x;
    if (kb < NB)
        gnn_body<2>(smem, (int)kb, 0, xb_cur, xb_nxt, esd_cur, esd_nxt, cst, pck, wvb, Wp, gatb,
                    lngp + (size_t)(l * 3 + 1) * 128, lnbp + (size_t)(l * 3 + 1) * 128, l);
    else if (kb < 3 * NB) {
        unsigned t = kb - NB;
        gnn_body<1>(smem, (int)(t >> 1), (int)(t & 1), xb_cur, xb_nxt, esd_cur, esd_nxt, cst, pck, wvb, Wp, gatb,
                    lngp + (size_t)(l * 3 + 2) * 128, lnbp + (size_t)(l * 3 + 2) * 128, l);
    } else
        gnn_body<0>(smem, (int)(kb - 3 * NB), 0, xb_cur, xb_nxt, esd_cur, esd_nxt, cst, pck, wvb, Wp, gatb,
                    lngp + (size_t)(l * 3 + 0) * 128, lnbp + (size_t)(l * 3 + 0) * 128, l);
}

/* ---------------- fused head: pools + player gather + MLP1 + MLP2 (256 threads) ---------------- */
__global__ __launch_bounds__(256) void k_head(const ushort_t* __restrict__ xb, const float* __restrict__ playerf,
                                              const int* __restrict__ curp,
                                              const float* __restrict__ W1, const float* __restrict__ b1,
                                              const float* __restrict__ W2, const float* __restrict__ b2,
                                              float* __restrict__ out) {
    __shared__ float fs[POOLD];
    __shared__ float ps[256];
    __shared__ float h1s[HID];
    int b = blockIdx.x, t = threadIdx.x;
    int c = t & 127, half = t >> 7;
    const ushort_t* xbb = xb + (size_t)b * NNODE * HID;
    float s0 = 0.f, s1 = 0.f, s2 = 0.f;
    for (int n = half; n < NHEX; n += 2)                    s0 += bf2f(xbb[n * HID + c]);
    for (int n = NHEX + half; n < NHEX + NVERT; n += 2)     s1 += bf2f(xbb[n * HID + c]);
    for (int n = NHEX + NVERT + half; n < NNODE; n += 2)    s2 += bf2f(xbb[n * HID + c]);
    ps[t] = s0; __syncthreads();
    if (half == 0) fs[c] = (ps[c] + ps[128 + c]) * (1.f / 19.f);
    __syncthreads(); ps[t] = s1; __syncthreads();
    if (half == 0) fs[128 + c] = (ps[c] + ps[128 + c]) * (1.f / 54.f);
    __syncthreads(); ps[t] = s2; __syncthreads();
    if (half == 0) fs[256 + c] = (ps[c] + ps[128 + c]) * (1.f / 72.f);
    if (t < FPLY) fs[384 + t] = playerf[((size_t)b * 4 + curp[b]) * FPLY + t];
    __syncthreads();
    float a = 0.f;
    int k0 = half * 199, k1 = half ? POOLD : 199;
    for (int k = k0; k < k1; ++k) a += fs[k] * W1[(size_t)k * HID + c];
    ps[t] = a; __syncthreads();
    if (half == 0) h1s[c] = fmaxf(b1[c] + ps[c] + ps[128 + c], 0.f);
    __syncthreads();
    float o = b2[t];
    for (int j = 0; j < HID; ++j) o += h1s[j] * W2[(size_t)j * OUTD + t];
    out[(size_t)b * OUTD + t] = o;
}

/* ---------------- workspace layout ---------------- */
static constexpr size_t alignUp(size_t v) { return (v + 255) & ~(size_t)255; }
static constexpr size_t OFF_CST  = 0;
static constexpr size_t OFF_PCK  = alignUp(OFF_CST + 5 * 73 * 4);
static constexpr size_t OFF_WVB  = alignUp(OFF_PCK + 5 * 144 * 4);
static constexpr size_t OFF_WP   = alignUp(OFF_WVB + (size_t)15 * 16 * 128 * 2);
static constexpr size_t OFF_XA   = alignUp(OFF_WP + (size_t)15 * 4 * 128 * 128 * 2);
static constexpr size_t OFF_XB2  = alignUp(OFF_XA + (size_t)NB * NNODE * HID * 2);
static constexpr size_t OFF_ESD0 = alignUp(OFF_XB2 + (size_t)NB * NNODE * HID * 2);
static constexpr size_t OFF_ESD1 = alignUp(OFF_ESD0 + (size_t)NB * ESD_PB * 4);

extern "C" void kernel_launch(void* const* d_in, const int* in_sizes, int n_in,
                              void* d_out, int out_size, void* d_ws, size_t ws_size,
                              hipStream_t stream) {
    (void)in_sizes; (void)n_in; (void)out_size; (void)ws_size;
    const float* hexf   = (const float*)d_in[0];
    const float* vertf  = (const float*)d_in[1];
    const float* edgef  = (const float*)d_in[2];
    const float* playerf= (const float*)d_in[3];
    const float* inhW   = (const float*)d_in[4];
    const float* inhb   = (const float*)d_in[5];
    const float* invW   = (const float*)d_in[6];
    const float* invb   = (const float*)d_in[7];
    const float* ineW   = (const float*)d_in[8];
    const float* ineb   = (const float*)d_in[9];
    const float* gatW   = (const float*)d_in[10];
    const float* gatas  = (const float*)d_in[11];
    const float* gatad  = (const float*)d_in[12];
    const float* gatb   = (const float*)d_in[13];
    const float* lngp   = (const float*)d_in[14];
    const float* lnbp   = (const float*)d_in[15];
    const float* mW1    = (const float*)d_in[16];
    const float* mb1    = (const float*)d_in[17];
    const float* mW2    = (const float*)d_in[18];
    const float* mb2    = (const float*)d_in[19];
    const int*   curp   = (const int*)d_in[20];
    float* out = (float*)d_out;

    char* ws = (char*)d_ws;
    int* cst        = (int*)(ws + OFF_CST);
    unsigned* pck   = (unsigned*)(ws + OFF_PCK);
    ushort_t* wvb   = (ushort_t*)(ws + OFF_WVB);
    ushort_t* Wp    = (ushort_t*)(ws + OFF_WP);
    ushort_t* xbA   = (ushort_t*)(ws + OFF_XA);
    ushort_t* xbB   = (ushort_t*)(ws + OFF_XB2);
    float* esd0     = (float*)(ws + OFF_ESD0);
    float* esd1     = (float*)(ws + OFF_ESD1);

    k_preA<<<76, 256, PREA_SMEM, stream>>>(cst, pck, gatW, gatas, gatad, wvb, Wp);
    k_projlog<<<NB, 256, PROJLOG_SMEM, stream>>>(hexf, vertf, edgef, inhW, inhb, invW, invb,
                                                 ineW, ineb, xbA, wvb, esd0);

    for (int l = 0; l < NLAYERS; ++l) {
        const ushort_t* cur = (l & 1) ? xbB : xbA;
        ushort_t* nxt = (l & 1) ? xbA : xbB;
        const float* ecur = (l & 1) ? esd1 : esd0;
        float* enxt = (l == 2) ? nullptr : ((l & 1) ? esd0 : esd1);
        k_layer<<<4 * NB, 256, SMEM_TOT, stream>>>(cur, nxt, ecur, enxt, cst, pck, wvb, Wp,
                                                   gatb, lngp, lnbp, l);
    }

    k_head<<<NB, 256, 0, stream>>>(xbB, playerf, curp, mW1, mb1, mW2, mb2, out);
}

// Round 18
// 736.264 us; speedup vs baseline: 1.3608x; 1.0580x over previous
//
#include <hip/hip_runtime.h>
#include <math.h>

#define NB 1024
#define NHEX 19
#define NVERT 54
#define NEDGE 72
#define NNODE 145   /* hex[0,19) vert[19,73) edge[73,145) */
#define HID 128
#define NLAYERS 3
#define MAXE 144
#define OUTD 256
#define FPLY 14
#define POOLD 398
#define ESD_PB 5120   /* floats per batch elem: 5 rels x 128 rows x 8 */

typedef unsigned short ushort_t;
typedef short bf16x8 __attribute__((ext_vector_type(8)));
typedef float f32x4 __attribute__((ext_vector_type(4)));
typedef float f32x2 __attribute__((ext_vector_type(2)));

static __device__ __forceinline__ float bf2f(ushort_t u) {
    return __uint_as_float(((unsigned int)u) << 16);
}
static __device__ __forceinline__ ushort_t f2bf(float f) {
    unsigned int u = __float_as_uint(f);
    return (ushort_t)((u + 0x7fffu + ((u >> 16) & 1u)) >> 16);
}
static __device__ __forceinline__ unsigned pk2(float lo, float hi) {
    unsigned r;
    asm("v_cvt_pk_bf16_f32 %0, %1, %2" : "=v"(r) : "v"(lo), "v"(hi));
    return r;
}
static __device__ __forceinline__ float blo(unsigned u) { return __uint_as_float(u << 16); }
static __device__ __forceinline__ float bhi(unsigned u) { return __uint_as_float(u & 0xffff0000u); }
static __device__ __forceinline__ f32x4 MF(uint4 a, uint4 b, f32x4 c) {
    return __builtin_amdgcn_mfma_f32_16x16x32_bf16(
        __builtin_bit_cast(bf16x8, a), __builtin_bit_cast(bf16x8, b), c, 0, 0, 0);
}
static __device__ __forceinline__ int xba(int row, int cb) {
    return (row * 256 + cb) ^ ((row & 7) << 4);
}

/* ================= topology (numpy RandomState(0) replica) + dedup CSR ============
   Dense dedup: edge-parallel atomic histogram M[Nd][Ns] -> parallel count/scan/rank. */
__device__ void topo_body(char* sm, int* __restrict__ cst_g, unsigned* __restrict__ pck_g) {
    unsigned* mt = (unsigned*)(sm);
    int* t6   = (int*)(sm + 2496);
    int* sc   = (int*)(sm + 4992);
    int* hv   = (int*)(sm + 7488);
    int* v0a  = (int*)(sm + 7944);
    int* v1a  = (int*)(sm + 8232);
    int* cnt  = (int*)(sm + 8520);
    int* cnt0 = (int*)(sm + 8840);
    int* stt  = (int*)(sm + 9160);
    int* J186 = (int*)(sm + 9480);
    int* M    = (int*)(sm + 9488);
    const int tid = threadIdx.x;

    if (tid == 0) {
        unsigned s = 0u;
        for (int i = 0; i < 624; ++i) { mt[i] = s; s = 1812433253u * (s ^ (s >> 30)) + (unsigned)i + 1u; }
    }
    __syncthreads();
    {
        unsigned a = 0, bb = 0, c = 0;
        if (tid < 227) { a = mt[tid]; bb = mt[tid + 1]; c = mt[tid + 397]; }
        __syncthreads();
        if (tid < 227) {
            unsigned y = (a & 0x80000000u) | (bb & 0x7fffffffu);
            mt[tid] = c ^ (y >> 1) ^ ((bb & 1u) ? 0x9908b0dfu : 0u);
        }
        __syncthreads();
    }
    {
        int i = 227 + tid;
        unsigned a = 0, bb = 0, c = 0;
        if (tid < 227) { a = mt[i]; bb = mt[i + 1]; c = mt[i - 227]; }
        __syncthreads();
        if (tid < 227) {
            unsigned y = (a & 0x80000000u) | (bb & 0x7fffffffu);
            mt[i] = c ^ (y >> 1) ^ ((bb & 1u) ? 0x9908b0dfu : 0u);
        }
        __syncthreads();
    }
    {
        int i = 454 + tid;
        unsigned a = 0, bb = 0, c = 0;
        if (tid < 170) { a = mt[i]; bb = mt[(i + 1) % 624]; c = mt[i - 227]; }
        __syncthreads();
        if (tid < 170) {
            unsigned y = (a & 0x80000000u) | (bb & 0x7fffffffu);
            mt[i] = c ^ (y >> 1) ^ ((bb & 1u) ? 0x9908b0dfu : 0u);
        }
        __syncthreads();
    }
    for (int i = tid; i < 624; i += 256) {
        unsigned y = mt[i];
        y ^= y >> 11; y ^= (y << 7) & 0x9d2c5680u; y ^= (y << 15) & 0xefc60000u; y ^= y >> 18;
        t6[i] = (int)(y & 63u);
    }
    __syncthreads();
#define SCAN624()                                                          \
    for (int off = 1; off < 624; off <<= 1) {                              \
        int v0_ = 0, v1_ = 0, v2_ = 0;                                     \
        int i0 = tid, i1 = tid + 256, i2 = tid + 512;                      \
        if (i0 >= off) v0_ = sc[i0 - off];                                 \
        if (i1 >= off) v1_ = sc[i1 - off];                                 \
        if (i2 < 624 && i2 >= off) v2_ = sc[i2 - off];                     \
        __syncthreads();                                                   \
        sc[i0] += v0_; sc[i1] += v1_;                                      \
        if (i2 < 624) sc[i2] += v2_;                                       \
        __syncthreads();                                                   \
    }
    for (int i = tid; i < 624; i += 256) sc[i] = (t6[i] <= 53) ? 1 : 0;
    __syncthreads();
    SCAN624();
    for (int i = tid; i < 624; i += 256) {
        if (t6[i] <= 53) {
            int k = sc[i];
            if (k <= 114) hv[k - 1] = t6[i];
            else if (k <= 186) v0a[k - 115] = t6[i];
            if (k == 186) *J186 = i;
        }
    }
    __syncthreads();
    int Jcap = *J186;
    for (int i = tid; i < 624; i += 256) sc[i] = (i > Jcap && t6[i] <= 52) ? 1 : 0;
    __syncthreads();
    SCAN624();
    for (int i = tid; i < 624; i += 256) {
        if (i > Jcap && t6[i] <= 52) {
            int k = sc[i];
            if (k <= 72) v1a[k - 1] = (v0a[k - 1] + 1 + t6[i]) % 54;
        }
    }
    __syncthreads();
#undef SCAN624
    const int En[5]  = {114, 114, 144, 144, 144};
    const int Ndn[5] = {54, 19, 72, 54, 54};
    const int Nsn[5] = {19, 54, 54, 72, 54};
    for (int r = 0; r < 5; ++r) {
        const int E = En[r], Nd = Ndn[r], Ns = Nsn[r];
        const int tot = Nd * Ns;
        for (int i = tid; i < tot; i += 256) M[i] = 0;
        __syncthreads();
        for (int k = tid; k < E; k += 256) {
            int s, d;
            if (r == 0)      { s = k / 6; d = hv[k]; }
            else if (r == 1) { s = hv[k]; d = k / 6; }
            else if (r == 2) { s = (k & 1) ? v1a[k >> 1] : v0a[k >> 1]; d = k >> 1; }
            else if (r == 3) { s = k >> 1; d = (k & 1) ? v1a[k >> 1] : v0a[k >> 1]; }
            else             { s = (k < 72) ? v0a[k] : v1a[k - 72]; d = (k < 72) ? v1a[k] : v0a[k - 72]; }
            atomicAdd(&M[d * Ns + s], 1);
        }
        __syncthreads();
        if (tid < Nd) {
            int c = 0;
            const int base = tid * Ns;
            for (int s = 0; s < Ns; ++s) c += (M[base + s] != 0) ? 1 : 0;
            cnt[tid] = c;
            cnt0[tid] = c;
        }
        __syncthreads();
        for (int off = 1; off < 128; off <<= 1) {
            int v = 0;
            if (tid < Nd && tid >= off) v = cnt[tid - off];
            __syncthreads();
            if (tid < Nd && tid >= off) cnt[tid] += v;
            __syncthreads();
        }
        if (tid < Nd) {
            int st = cnt[tid] - cnt0[tid];
            stt[tid] = st;
            cst_g[r * 73 + tid] = st;
            if (tid == Nd - 1) cst_g[r * 73 + Nd] = cnt[tid];
        }
        __syncthreads();
        for (int i = tid; i < tot; i += 256) {
            int m = M[i];
            if (m > 0) {
                int d = i / Ns, s = i - d * Ns;
                int rank = 0;
                const int base = d * Ns;
                for (int s2 = 0; s2 < s; ++s2) rank += (M[base + s2] != 0) ? 1 : 0;
                pck_g[r * 144 + stt[d] + rank] = (unsigned)(s | (d << 8) | (m << 16));
            }
        }
        __syncthreads();
    }
}

/* -------- attention vectors, packed 16-vec tile: h=was_hi, 4+h=wad_hi, 8+h=was_lo, 12+h=wad_lo -- */
__device__ void wvec_body(char* sm, int lr, const float* __restrict__ gat_W,
                          const float* __restrict__ gat_asrc,
                          const float* __restrict__ gat_adst,
                          ushort_t* __restrict__ wvb) {
    float* as_s = (float*)(sm);
    float* ad_s = (float*)(sm + 2048);
    int tid = threadIdx.x;
    for (int i = tid; i < 512; i += 256) {
        as_s[i] = gat_asrc[(size_t)lr * 512 + i];
        ad_s[i] = gat_adst[(size_t)lr * 512 + i];
    }
    __syncthreads();
    ushort_t* wb = wvb + (size_t)lr * 2048;
    const float* W = gat_W + (size_t)lr * 128 * 512;
    int t127 = tid & 127, rhalf = tid >> 7;
    int h = t127 >> 5, c4 = t127 & 31;
    for (int k0 = 0; k0 < 128; k0 += 2) {
        int k = k0 + rhalf;
        float4 wv4 = *(const float4*)(W + (size_t)k * 512 + h * 128 + c4 * 4);
        const float* a = as_s + h * 128 + c4 * 4;
        const float* dd = ad_s + h * 128 + c4 * 4;
        float pa = wv4.x * a[0] + wv4.y * a[1] + wv4.z * a[2] + wv4.w * a[3];
        float pd = wv4.x * dd[0] + wv4.y * dd[1] + wv4.z * dd[2] + wv4.w * dd[3];
        for (int m = 1; m < 32; m <<= 1) { pa += __shfl_xor(pa, m, 64); pd += __shfl_xor(pd, m, 64); }
        if (c4 == 0) {
            ushort_t pah = f2bf(pa), pdh = f2bf(pd);
            ushort_t pal = f2bf(pa - bf2f(pah)), pdl = f2bf(pd - bf2f(pdh));
            wb[h * 128 + k] = pah;        wb[(4 + h) * 128 + k] = pdh;
            wb[(8 + h) * 128 + k] = pal;  wb[(12 + h) * 128 + k] = pdl;
        }
    }
}

/* -------- Wp[lr][h][n][k] = bf16(gat_W[lr][k][h*128+n]) — two 64-row passes -- */
__device__ void wp_body(char* sm, int lrh, const float* __restrict__ gat_W, ushort_t* __restrict__ Wp) {
    ushort_t* tr = (ushort_t*)(sm);     /* [64][130] */
    int lr = lrh >> 2, h = lrh & 3;
    const float* Wsrc = gat_W + (size_t)lr * 128 * 512 + h * 128;
    ushort_t* dst = Wp + (size_t)lrh * 128 * 128;
    for (int half = 0; half < 2; ++half) {
        for (int i = threadIdx.x; i < 128 * 16; i += 256) {
            int k = i >> 4, q2 = i & 15;
            float4 v = *(const float4*)(Wsrc + (size_t)k * 512 + half * 64 + q2 * 4);
            int nl = q2 * 4;
            tr[(nl + 0) * 130 + k] = f2bf(v.x);
            tr[(nl + 1) * 130 + k] = f2bf(v.y);
            tr[(nl + 2) * 130 + k] = f2bf(v.z);
            tr[(nl + 3) * 130 + k] = f2bf(v.w);
        }
        __syncthreads();
        for (int i = threadIdx.x; i < 64 * 16; i += 256) {
            int nl = i >> 4, q = i & 15;
            const ushort_t* s = tr + nl * 130 + q * 8;
            uint4 o;
            o.x = (unsigned)s[0] | ((unsigned)s[1] << 16);
            o.y = (unsigned)s[2] | ((unsigned)s[3] << 16);
            o.z = (unsigned)s[4] | ((unsigned)s[5] << 16);
            o.w = (unsigned)s[6] | ((unsigned)s[7] << 16);
            *(uint4*)(dst + (half * 64 + nl) * 128 + q * 8) = o;
        }
        __syncthreads();
    }
}

/* merged prologue: block 0 topo | 1-15 wvec | 16-75 wp — shared dynamic LDS (25 KB) */
__global__ __launch_bounds__(256) void k_preA(
        int* __restrict__ cst_g, unsigned* __restrict__ pck_g,
        const float* __restrict__ gatW, const float* __restrict__ gatas,
        const float* __restrict__ gatad, ushort_t* __restrict__ wvb, ushort_t* __restrict__ Wp) {
    extern __shared__ char smem_dyn[];
    unsigned kb = blockIdx.x;
    if (kb == 0)      topo_body(smem_dyn, cst_g, pck_g);
    else if (kb < 16) wvec_body(smem_dyn, (int)kb - 1, gatW, gatas, gatad, wvb);
    else              wp_body(smem_dyn, (int)kb - 16, gatW, Wp);
}
#define PREA_SMEM 25088

/* -------- fused proj + layer-0 logits, per batch block.
   R18: W/b read directly from global (L2-hot) — LDS = X tile only (37120 B -> 4 blocks/CU),
   one less barrier. R12-R17 evidence: occupancy dominates micro-costs in this regime. -------- */
__global__ __launch_bounds__(256) void k_projlog(
        const float* __restrict__ hexf, const float* __restrict__ vertf,
        const float* __restrict__ edgef,
        const float* __restrict__ Wh, const float* __restrict__ bh,
        const float* __restrict__ Wv, const float* __restrict__ bv,
        const float* __restrict__ We, const float* __restrict__ be,
        ushort_t* __restrict__ xb, const ushort_t* __restrict__ wvb,
        float* __restrict__ esd_g) {
    extern __shared__ char smem_dyn[];
    char*  smem = smem_dyn;
    int b = blockIdx.x, tid = threadIdx.x, lane = tid & 63, wid = tid >> 6;
    const int kc16 = (lane >> 4) * 16;

    int c = tid & 127;
    for (int n = tid >> 7; n < NNODE; n += 2) {
        const float* f; const float* W; const float* bias; int K;
        if (n < NHEX)              { f = hexf  + ((size_t)b * NHEX  + n) * 9;                  W = Wh; bias = bh; K = 9; }
        else if (n < NHEX + NVERT) { f = vertf + ((size_t)b * NVERT + (n - NHEX)) * 7;         W = Wv; bias = bv; K = 7; }
        else                       { f = edgef + ((size_t)b * NEDGE + (n - NHEX - NVERT)) * 5; W = We; bias = be; K = 5; }
        float acc = bias[c];
        for (int k = 0; k < K; ++k) acc += f[k] * W[k * 128 + c];
        ushort_t u = f2bf(acc);
        xb[((size_t)b * NNODE + n) * HID + c] = u;
        *(ushort_t*)(smem + xba(n, c * 2)) = u;
    }
    __syncthreads();

    const int NsA[5] = {19, 54, 54, 72, 54}, SbA[5] = {0, 19, 19, 73, 19};
    const int NdA[5] = {54, 19, 72, 54, 54}, DbA[5] = {19, 0, 73, 19, 19};
    for (int r = 0; r < 5; ++r) {
        int Ns = NsA[r];
        int RL = (r == 4) ? 54 : Ns + NdA[r];
        const ushort_t* wv = wvb + (size_t)r * 2048;
        uint4 bw[4];
#pragma unroll
        for (int ks = 0; ks < 4; ++ks)
            bw[ks] = *(const uint4*)(wv + (lane & 15) * 128 + ks * 32 + (lane >> 4) * 8);
        int T = (RL + 15) >> 4;
        for (int t = wid; t < T; t += 4) {
            int vrow = t * 16 + (lane & 15);
            int node = vrow < Ns ? SbA[r] + vrow : (vrow < RL ? DbA[r] + (vrow - Ns) : SbA[r]);
            f32x4 e = (f32x4){0.f, 0.f, 0.f, 0.f};
#pragma unroll
            for (int ks = 0; ks < 4; ++ks)
                e = MF(*(const uint4*)(smem + xba(node, ks * 64 + kc16)), bw[ks], e);
#pragma unroll
            for (int g = 0; g < 4; ++g) {
                float sv = e[g] + __shfl_xor(e[g], 8, 64);
                int row = t * 16 + (lane >> 4) * 4 + g;
                if ((lane & 15) < 8 && row < RL)
                    esd_g[(size_t)b * ESD_PB + r * 1024 + row * 8 + (lane & 15)] = sv;
            }
        }
    }
}
#define PROJLOG_SMEM 37120

/* =========== fused body: stage + softmax + y-build + MFMA2 + LN + next-layer logits.
   KIND1 (edge) runs as 2 half-blocks of 36 rows (MT 5->3, spill fix, R11 post-mortem). ===== */
template<int KIND>
__device__ __forceinline__ void gnn_body(char* smem, int b, int half,
        const ushort_t* __restrict__ xb_cur, ushort_t* __restrict__ xb_nxt,
        const float* __restrict__ esd_cur, float* __restrict__ esd_nxt,
        const int* __restrict__ cst_all, const unsigned* __restrict__ pck_all,
        const ushort_t* __restrict__ wvb, const ushort_t* __restrict__ Wp_g,
        const float* __restrict__ gatb_g,
        const float* __restrict__ lg, const float* __restrict__ lb, int l) {
    constexpr int ND    = (KIND == 0 ? 19 : KIND == 1 ? 36 : 54);
    constexpr int DBASE = (KIND == 0 ? 0 : KIND == 1 ? 73 : 19);
    constexpr int NSMAX = (KIND == 2 ? 72 : 54);
    constexpr int NRELF = (KIND == 2 ? 3 : 1);
    constexpr int MT    = (ND + 15) / 16;
    constexpr int O_Y   = NSMAX * 256;
    constexpr int O_ESD = O_Y + ND * 256;
    constexpr int O_AL  = O_ESD + 4064;
    constexpr int O_CST = O_AL + 2304;
    constexpr int O_PCK = O_CST + 304;

    constexpr int NS_A[3][3] = {{54, 0, 0}, {54, 0, 0}, {19, 72, 54}};
    constexpr int SB_A[3][3] = {{19, 0, 0}, {19, 0, 0}, {0, 73, 19}};
    constexpr int RR_A[3][3] = {{1, 0, 0}, {2, 0, 0}, {0, 3, 4}};
    constexpr int NRE = (KIND == 2 ? 5 : 2);
    constexpr int RE_R[3][5] = {{0, 1, 0, 0, 0}, {2, 3, 0, 0, 0}, {0, 1, 2, 3, 4}};
    constexpr int RE_B[3][5] = {{0, 54, 0, 0, 0}, {54, 0, 0, 0, 0}, {19, 0, 0, 72, 0}};

    float*    esdL = (float*)(smem + O_ESD);
    float*    alph = (float*)(smem + O_AL);
    int*      cstL = (int*)(smem + O_CST);
    unsigned* pckL = (unsigned*)(smem + O_PCK);

    const int tid = threadIdx.x, lane = tid & 63, wid = tid >> 6;
    const int nr0 = wid * 32 + (lane & 15);
    const int kc16 = (lane >> 4) * 16;
    const int d0 = half * ND;
    const int DB = DBASE + d0;
    const ushort_t* xcb = xb_cur + (size_t)b * NNODE * HID;

    f32x4 acc[MT][2];
#pragma unroll
    for (int mt = 0; mt < MT; ++mt) {
        acc[mt][0] = (f32x4){0.f, 0.f, 0.f, 0.f};
        acc[mt][1] = (f32x4){0.f, 0.f, 0.f, 0.f};
    }

#pragma unroll
    for (int ri = 0; ri < NRELF; ++ri) {
        const int NS = NS_A[KIND][ri], SBG = SB_A[KIND][ri], r = RR_A[KIND][ri];
        const bool SELF = (KIND == 2 && ri == 2);
        const int lr = l * 5 + r;
        const int ER = SELF ? ND : NS + ND;
        const int jlo = cst_all[r * 73 + d0];

        for (int i = tid; i < NS * 16; i += 256) {
            int row = i >> 4, q = i & 15;
            uint4 o = *(const uint4*)(xcb + (size_t)(SBG + row) * HID + q * 8);
            *(uint4*)(smem + xba(row, q * 16)) = o;
        }
        {
            const float* eg = esd_cur + (size_t)b * ESD_PB + (size_t)r * 1024;
            for (int i = tid; i < ER * 2; i += 256) {
                int row = i >> 1;
                int grow = (SELF || row < NS) ? row : row + d0;
                ((uint4*)esdL)[i] = ((const uint4*)eg)[grow * 2 + (i & 1)];
            }
        }
        for (int i = tid; i <= ND; i += 256) cstL[i] = cst_all[r * 73 + d0 + i] - jlo;
        for (int i = tid; jlo + i < 144; i += 256) pckL[i] = pck_all[r * 144 + jlo + i];
        __syncthreads();

        for (int i = tid; i < ND * 4; i += 256) {
            int d = i >> 2, h = i & 3;
            int s0 = cstL[d], s1 = cstL[d + 1];
            if (s0 == s1) continue;
            float edv = esdL[((SELF ? d + d0 : NS + d)) * 8 + 4 + h];
            float m = -1e30f;
            for (int j = s0; j < s1; ++j) {
                float sv = esdL[(pckL[j] & 255) * 8 + h] + edv;
                sv = (sv >= 0.f) ? sv : 0.2f * sv;
                alph[j * 4 + h] = sv;
                m = fmaxf(m, sv);
            }
            float sum = 0.f;
            for (int j = s0; j < s1; ++j) {
                float e = (float)(pckL[j] >> 16) * __expf(alph[j * 4 + h] - m);
                alph[j * 4 + h] = e;
                sum += e;
            }
            float inv = 1.f / (sum + 1e-16f);
            for (int j = s0; j < s1; ++j) alph[j * 4 + h] *= inv;
        }
        __syncthreads();

        for (int h = 0; h < 4; ++h) {
            for (int i = tid; i < ND * 16; i += 256) {
                int d = i >> 4, c8 = i & 15;
                int s0 = cstL[d], s1 = cstL[d + 1];
                f32x2 a01 = (f32x2){0.f, 0.f}, a23 = (f32x2){0.f, 0.f};
                f32x2 a45 = (f32x2){0.f, 0.f}, a67 = (f32x2){0.f, 0.f};
                for (int j = s0; j < s1; ++j) {
                    float al = alph[j * 4 + h];
                    f32x2 al2 = (f32x2){al, al};
                    uint4 xv = *(const uint4*)(smem + xba((int)(pckL[j] & 255), c8 * 16));
                    a01 += al2 * (f32x2){blo(xv.x), bhi(xv.x)};
                    a23 += al2 * (f32x2){blo(xv.y), bhi(xv.y)};
                    a45 += al2 * (f32x2){blo(xv.z), bhi(xv.z)};
                    a67 += al2 * (f32x2){blo(xv.w), bhi(xv.w)};
                }
                uint4 o;
                o.x = pk2(a01[0], a01[1]); o.y = pk2(a23[0], a23[1]);
                o.z = pk2(a45[0], a45[1]); o.w = pk2(a67[0], a67[1]);
                *(uint4*)(smem + O_Y + xba(d, c8 * 16)) = o;
            }
            const ushort_t* wpH = Wp_g + (size_t)(lr * 4 + h) * 16384;
            __syncthreads();
#pragma unroll
            for (int ks = 0; ks < 4; ++ks) {
                uint4 b0 = *(const uint4*)(wpH + (size_t)nr0 * 128 + ks * 32 + (lane >> 4) * 8);
                uint4 b1 = *(const uint4*)(wpH + (size_t)(nr0 + 16) * 128 + ks * 32 + (lane >> 4) * 8);
#pragma unroll
                for (int mt = 0; mt < MT; ++mt) {
                    int arow = mt * 16 + (lane & 15);
                    if (arow >= ND) arow = ND - 1;
                    uint4 av = *(const uint4*)(smem + O_Y + xba(arow, ks * 64 + kc16));
                    acc[mt][0] = MF(av, b0, acc[mt][0]);
                    acc[mt][1] = MF(av, b1, acc[mt][1]);
                }
            }
            __syncthreads();
        }
    }

    /* epilogue */
    float bn0 = 0.f, bn1 = 0.f;
#pragma unroll
    for (int ri = 0; ri < NRELF; ++ri) {
        const float* bb = gatb_g + (size_t)(l * 5 + RR_A[KIND][ri]) * 128;
        bn0 += bb[nr0]; bn1 += bb[nr0 + 16];
    }
    const float lgc0 = lg[nr0], lgc1 = lg[nr0 + 16];
    const float lbc0 = lb[nr0], lbc1 = lb[nr0 + 16];
#pragma unroll
    for (int mt = 0; mt < MT; ++mt)
#pragma unroll
        for (int g = 0; g < 4; ++g) {
            int row = mt * 16 + (lane >> 4) * 4 + g;
            if (row < ND) {
                acc[mt][0][g] = 0.25f * acc[mt][0][g] + bn0 + bf2f(xcb[(size_t)(DB + row) * HID + nr0]);
                acc[mt][1][g] = 0.25f * acc[mt][1][g] + bn1 + bf2f(xcb[(size_t)(DB + row) * HID + nr0 + 16]);
            }
        }
    float* red1 = esdL;
    float* red2 = esdL + 320;
#pragma unroll
    for (int mt = 0; mt < MT; ++mt)
#pragma unroll
        for (int g = 0; g < 4; ++g) {
            float p = acc[mt][0][g] + acc[mt][1][g];
            for (int m = 1; m < 16; m <<= 1) p += __shfl_xor(p, m, 64);
            int row = mt * 16 + (lane >> 4) * 4 + g;
            if ((lane & 15) == 0 && row < ND) red1[row * 4 + wid] = p;
        }
    __syncthreads();
#pragma unroll
    for (int mt = 0; mt < MT; ++mt)
#pragma unroll
        for (int g = 0; g < 4; ++g) {
            int row = mt * 16 + (lane >> 4) * 4 + g;
            float mu = 0.f;
            if (row < ND)
                mu = (red1[row * 4] + red1[row * 4 + 1] + red1[row * 4 + 2] + red1[row * 4 + 3]) * (1.f / 128.f);
            acc[mt][0][g] -= mu;
            acc[mt][1][g] -= mu;
            float p = acc[mt][0][g] * acc[mt][0][g] + acc[mt][1][g] * acc[mt][1][g];
            for (int m = 1; m < 16; m <<= 1) p += __shfl_xor(p, m, 64);
            if ((lane & 15) == 0 && row < ND) red2[row * 4 + wid] = p;
        }
    __syncthreads();
#pragma unroll
    for (int mt = 0; mt < MT; ++mt)
#pragma unroll
        for (int g = 0; g < 4; ++g) {
            int row = mt * 16 + (lane >> 4) * 4 + g;
            if (row < ND) {
                float var = (red2[row * 4] + red2[row * 4 + 1] + red2[row * 4 + 2] + red2[row * 4 + 3]) * (1.f / 128.f);
                float rs = rsqrtf(var + 1e-5f);
                float o0 = fmaxf(acc[mt][0][g] * rs * lgc0 + lbc0, 0.f);
                float o1 = fmaxf(acc[mt][1][g] * rs * lgc1 + lbc1, 0.f);
                size_t gi = ((size_t)b * NNODE + DB + row) * HID;
                ushort_t u0 = f2bf(o0), u1 = f2bf(o1);
                xb_nxt[gi + nr0] = u0;
                xb_nxt[gi + nr0 + 16] = u1;
                if (esd_nxt) {
                    *(ushort_t*)(smem + O_Y + xba(row, nr0 * 2)) = u0;
                    *(ushort_t*)(smem + O_Y + xba(row, (nr0 + 16) * 2)) = u1;
                }
            }
        }
    if (esd_nxt) {
        __syncthreads();
        const int T = (ND + 15) >> 4;
        for (int t5 = wid; t5 < NRE * T; t5 += 4) {
            int e = t5 / T, tt = t5 % T;
            int r2 = RE_R[KIND][e], base = RE_B[KIND][e] + d0;
            const ushort_t* wv = wvb + (size_t)((l + 1) * 5 + r2) * 2048;
            uint4 bw[4];
#pragma unroll
            for (int ks = 0; ks < 4; ++ks)
                bw[ks] = *(const uint4*)(wv + (lane & 15) * 128 + ks * 32 + (lane >> 4) * 8);
            int arow = tt * 16 + (lane & 15);
            if (arow >= ND) arow = ND - 1;
            f32x4 ev = (f32x4){0.f, 0.f, 0.f, 0.f};
#pragma unroll
            for (int ks = 0; ks < 4; ++ks)
                ev = MF(*(const uint4*)(smem + O_Y + xba(arow, ks * 64 + kc16)), bw[ks], ev);
#pragma unroll
            for (int g = 0; g < 4; ++g) {
                float sv = ev[g] + __shfl_xor(ev[g], 8, 64);
                int row = tt * 16 + (lane >> 4) * 4 + g;
                if ((lane & 15) < 8 && row < ND)
                    esd_nxt[(size_t)b * ESD_PB + r2 * 1024 + (base + row) * 8 + (lane & 15)] = sv;
            }
        }
    }
}

#define SMEM_TOT 39504

__global__ __launch_bounds__(256, 4) void k_layer(
        const ushort_t* __restrict__ xb_cur, ushort_t* __restrict__ xb_nxt,
        const float* __restrict__ esd_cur, float* __restrict__ esd_nxt,
        const int* __restrict__ cst, const unsigned* __restrict__ pck,
        const ushort_t* __restrict__ wvb, const ushort_t* __restrict__ Wp,
        const float* __restrict__ gatb, const float* __restrict__ lngp,
        const float* __restrict__ lnbp, int l) {
    extern __shared__ uint4 smem_u4[];
    char* smem = (char*)smem_u4;
    unsigned kb = blockIdx.x;
    if (kb < NB)
        gnn_body<2>(smem, (int)kb, 0, xb_cur, xb_nxt, esd_cur, esd_nxt, cst, pck, wvb, Wp, gatb,
                    lngp + (size_t)(l * 3 + 1) * 128, lnbp + (size_t)(l * 3 + 1) * 128, l);
    else if (kb < 3 * NB) {
        unsigned t = kb - NB;
        gnn_body<1>(smem, (int)(t >> 1), (int)(t & 1), xb_cur, xb_nxt, esd_cur, esd_nxt, cst, pck, wvb, Wp, gatb,
                    lngp + (size_t)(l * 3 + 2) * 128, lnbp + (size_t)(l * 3 + 2) * 128, l);
    } else
        gnn_body<0>(smem, (int)(kb - 3 * NB), 0, xb_cur, xb_nxt, esd_cur, esd_nxt, cst, pck, wvb, Wp, gatb,
                    lngp + (size_t)(l * 3 + 0) * 128, lnbp + (size_t)(l * 3 + 0) * 128, l);
}

/* ---------------- fused head: pools + player gather + MLP1 + MLP2 (256 threads) ---------------- */
__global__ __launch_bounds__(256) void k_head(const ushort_t* __restrict__ xb, const float* __restrict__ playerf,
                                              const int* __restrict__ curp,
                                              const float* __restrict__ W1, const float* __restrict__ b1,
                                              const float* __restrict__ W2, const float* __restrict__ b2,
                                              float* __restrict__ out) {
    __shared__ float fs[POOLD];
    __shared__ float ps[256];
    __shared__ float h1s[HID];
    int b = blockIdx.x, t = threadIdx.x;
    int c = t & 127, half = t >> 7;
    const ushort_t* xbb = xb + (size_t)b * NNODE * HID;
    float s0 = 0.f, s1 = 0.f, s2 = 0.f;
    for (int n = half; n < NHEX; n += 2)                    s0 += bf2f(xbb[n * HID + c]);
    for (int n = NHEX + half; n < NHEX + NVERT; n += 2)     s1 += bf2f(xbb[n * HID + c]);
    for (int n = NHEX + NVERT + half; n < NNODE; n += 2)    s2 += bf2f(xbb[n * HID + c]);
    ps[t] = s0; __syncthreads();
    if (half == 0) fs[c] = (ps[c] + ps[128 + c]) * (1.f / 19.f);
    __syncthreads(); ps[t] = s1; __syncthreads();
    if (half == 0) fs[128 + c] = (ps[c] + ps[128 + c]) * (1.f / 54.f);
    __syncthreads(); ps[t] = s2; __syncthreads();
    if (half == 0) fs[256 + c] = (ps[c] + ps[128 + c]) * (1.f / 72.f);
    if (t < FPLY) fs[384 + t] = playerf[((size_t)b * 4 + curp[b]) * FPLY + t];
    __syncthreads();
    float a = 0.f;
    int k0 = half * 199, k1 = half ? POOLD : 199;
    for (int k = k0; k < k1; ++k) a += fs[k] * W1[(size_t)k * HID + c];
    ps[t] = a; __syncthreads();
    if (half == 0) h1s[c] = fmaxf(b1[c] + ps[c] + ps[128 + c], 0.f);
    __syncthreads();
    float o = b2[t];
    for (int j = 0; j < HID; ++j) o += h1s[j] * W2[(size_t)j * OUTD + t];
    out[(size_t)b * OUTD + t] = o;
}

/* ---------------- workspace layout ---------------- */
static constexpr size_t alignUp(size_t v) { return (v + 255) & ~(size_t)255; }
static constexpr size_t OFF_CST  = 0;
static constexpr size_t OFF_PCK  = alignUp(OFF_CST + 5 * 73 * 4);
static constexpr size_t OFF_WVB  = alignUp(OFF_PCK + 5 * 144 * 4);
static constexpr size_t OFF_WP   = alignUp(OFF_WVB + (size_t)15 * 16 * 128 * 2);
static constexpr size_t OFF_XA   = alignUp(OFF_WP + (size_t)15 * 4 * 128 * 128 * 2);
static constexpr size_t OFF_XB2  = alignUp(OFF_XA + (size_t)NB * NNODE * HID * 2);
static constexpr size_t OFF_ESD0 = alignUp(OFF_XB2 + (size_t)NB * NNODE * HID * 2);
static constexpr size_t OFF_ESD1 = alignUp(OFF_ESD0 + (size_t)NB * ESD_PB * 4);

extern "C" void kernel_launch(void* const* d_in, const int* in_sizes, int n_in,
                              void* d_out, int out_size, void* d_ws, size_t ws_size,
                              hipStream_t stream) {
    (void)in_sizes; (void)n_in; (void)out_size; (void)ws_size;
    const float* hexf   = (const float*)d_in[0];
    const float* vertf  = (const float*)d_in[1];
    const float* edgef  = (const float*)d_in[2];
    const float* playerf= (const float*)d_in[3];
    const float* inhW   = (const float*)d_in[4];
    const float* inhb   = (const float*)d_in[5];
    const float* invW   = (const float*)d_in[6];
    const float* invb   = (const float*)d_in[7];
    const float* ineW   = (const float*)d_in[8];
    const float* ineb   = (const float*)d_in[9];
    const float* gatW   = (const float*)d_in[10];
    const float* gatas  = (const float*)d_in[11];
    const float* gatad  = (const float*)d_in[12];
    const float* gatb   = (const float*)d_in[13];
    const float* lngp   = (const float*)d_in[14];
    const float* lnbp   = (const float*)d_in[15];
    const float* mW1    = (const float*)d_in[16];
    const float* mb1    = (const float*)d_in[17];
    const float* mW2    = (const float*)d_in[18];
    const float* mb2    = (const float*)d_in[19];
    const int*   curp   = (const int*)d_in[20];
    float* out = (float*)d_out;

    char* ws = (char*)d_ws;
    int* cst        = (int*)(ws + OFF_CST);
    unsigned* pck   = (unsigned*)(ws + OFF_PCK);
    ushort_t* wvb   = (ushort_t*)(ws + OFF_WVB);
    ushort_t* Wp    = (ushort_t*)(ws + OFF_WP);
    ushort_t* xbA   = (ushort_t*)(ws + OFF_XA);
    ushort_t* xbB   = (ushort_t*)(ws + OFF_XB2);
    float* esd0     = (float*)(ws + OFF_ESD0);
    float* esd1     = (float*)(ws + OFF_ESD1);

    k_preA<<<76, 256, PREA_SMEM, stream>>>(cst, pck, gatW, gatas, gatad, wvb, Wp);
    k_projlog<<<NB, 256, PROJLOG_SMEM, stream>>>(hexf, vertf, edgef, inhW, inhb, invW, invb,
                                                 ineW, ineb, xbA, wvb, esd0);

    for (int l = 0; l < NLAYERS; ++l) {
        const ushort_t* cur = (l & 1) ? xbB : xbA;
        ushort_t* nxt = (l & 1) ? xbA : xbB;
        const float* ecur = (l & 1) ? esd1 : esd0;
        float* enxt = (l == 2) ? nullptr : ((l & 1) ? esd0 : esd1);
        k_layer<<<4 * NB, 256, SMEM_TOT, stream>>>(cur, nxt, ecur, enxt, cst, pck, wvb, Wp,
                                                   gatb, lngp, lnbp, l);
    }

    k_head<<<NB, 256, 0, stream>>>(xbB, playerf, curp, mW1, mb1, mW2, mb2, out);
}